// Round 1
// baseline (758.938 us; speedup 1.0000x reference)
//
#include <hip/hip_runtime.h>
#include <hip/hip_bf16.h>
#include <math.h>

#define TB 4
#define TT 4096
#define HH 2048
#define DD 256
#define NN 32768
#define HQ 512
#define MM (TB*TT)

typedef __attribute__((ext_vector_type(8))) short bf16x8;
typedef __attribute__((ext_vector_type(8))) _Float16 f16x8;
typedef __attribute__((ext_vector_type(4))) float f32x4;

__device__ inline unsigned short f2bf(float x){
  __hip_bfloat16 h = __float2bfloat16(x);
  return *reinterpret_cast<unsigned short*>(&h);
}

__device__ inline unsigned short f2h(float x){
  _Float16 h = (_Float16)x;
  unsigned short u; __builtin_memcpy(&u, &h, 2); return u;
}

__device__ inline bf16x8 as_bf16x8(uint4 u){ bf16x8 r; __builtin_memcpy(&r,&u,16); return r; }

// K1: batch-mean only (bf16 out)
__global__ __launch_bounds__(256) void k_mean(const float* __restrict__ h,
    unsigned short* __restrict__ hmb){
  const size_t i = (size_t)blockIdx.x*256 + threadIdx.x;   // float4 idx in [T*H/4]
  const size_t TH4 = (size_t)TT*HH/4;
  const float4* p = (const float4*)h;
  float4 v0 = p[i], v1 = p[i+TH4], v2 = p[i+2*TH4], v3 = p[i+3*TH4];
  float4 m;
  m.x = 0.25f*(v0.x+v1.x+v2.x+v3.x);
  m.y = 0.25f*(v0.y+v1.y+v2.y+v3.y);
  m.z = 0.25f*(v0.z+v1.z+v2.z+v3.z);
  m.w = 0.25f*(v0.w+v1.w+v2.w+v3.w);
  ushort4 o; o.x = f2bf(m.x); o.y = f2bf(m.y); o.z = f2bf(m.z); o.w = f2bf(m.w);
  *(ushort4*)(hmb + i*4) = o;
}

// K2: W_g1||W_p1 -> fp16, pre-swizzled tile-linear layout for k_gp.
// Tiles: [nb 0..3][kc 0..63] of 256 rows x 32 halfs; within tile:
// addr = r*32 + ((c8 ^ s(r))<<3) + (k&7), s(r) = (r&3)^((r>>2)&3)
__global__ __launch_bounds__(256) void k_cvt_w(const float* __restrict__ Wg1,
    const float* __restrict__ Wp1, unsigned short* __restrict__ Wsw){
  const int id = blockIdx.x*256 + threadIdx.x;       // 262144 8-half chunks
  const int n = id >> 8;                             // row 0..1023
  const int cg = id & 255;                           // chunk in row
  const int k = cg*8;
  const int kc = cg >> 2;
  const int c8 = cg & 3;
  const float* src = (n < HQ) ? (Wg1 + (size_t)n*HH + k) : (Wp1 + (size_t)(n-HQ)*HH + k);
  float4 v0 = *(const float4*)src;
  float4 v1 = *(const float4*)(src + 4);
  unsigned short o[8] = {f2h(v0.x),f2h(v0.y),f2h(v0.z),f2h(v0.w),
                         f2h(v1.x),f2h(v1.y),f2h(v1.z),f2h(v1.w)};
  const int nb = n >> 8, r = n & 255;
  const int s = (r & 3) ^ ((r >> 2) & 3);
  unsigned short* dst = Wsw + ((size_t)(nb*64 + kc))*8192 + r*32 + ((c8 ^ s) << 3);
  __builtin_memcpy(dst, o, 16);
}

// K2b: W_obs -> bf16 [256,2048]
__global__ __launch_bounds__(256) void k_cvt_wobs(const float* __restrict__ W,
    unsigned short* __restrict__ Wb){
  const int idx4 = blockIdx.x*256 + threadIdx.x;     // 131072 float4s
  float4 v = *(const float4*)(W + (size_t)idx4*4);
  ushort4 o; o.x = f2bf(v.x); o.y = f2bf(v.y); o.z = f2bf(v.z); o.w = f2bf(v.w);
  *(ushort4*)(Wb + (size_t)idx4*4) = o;
}

// K3: obs_mean = hmb @ wob^T  (bf16 MFMA, f32 out)  [4096,2048]x[256,2048]^T
__global__ __launch_bounds__(256) void k_obs(const unsigned short* __restrict__ A,
    const unsigned short* __restrict__ Bw, float* __restrict__ C){
  const int n0 = blockIdx.x*128, m0 = blockIdx.y*128;
  const int tid = threadIdx.x;
  const int w = tid>>6, lane = tid&63, lr = lane&15, q = lane>>4;
  __shared__ __align__(16) unsigned short Bs[128][40];
  f32x4 acc[2][8] = {};
  for (int k0 = 0; k0 < HH; k0 += 32){
    __syncthreads();
    #pragma unroll
    for (int ii = 0; ii < 2; ii++){
      int idx = tid + ii*256;
      int row = idx >> 2, c8 = (idx & 3)*8;
      *(uint4*)&Bs[row][c8] = *(const uint4*)(Bw + (size_t)(n0+row)*HH + k0 + c8);
    }
    bf16x8 a[2];
    #pragma unroll
    for (int i = 0; i < 2; i++)
      a[i] = as_bf16x8(*(const uint4*)(A + (size_t)(m0 + w*32 + i*16 + lr)*HH + k0 + q*8));
    __syncthreads();
    #pragma unroll
    for (int j = 0; j < 8; j++){
      bf16x8 b = as_bf16x8(*(const uint4*)&Bs[j*16 + lr][q*8]);
      #pragma unroll
      for (int i = 0; i < 2; i++)
        acc[i][j] = __builtin_amdgcn_mfma_f32_16x16x32_bf16(a[i], b, acc[i][j], 0, 0, 0);
    }
  }
  #pragma unroll
  for (int i = 0; i < 2; i++)
    #pragma unroll
    for (int j = 0; j < 8; j++)
      #pragma unroll
      for (int r = 0; r < 4; r++)
        C[(size_t)(m0 + w*32 + i*16 + q*4 + r)*DD + n0 + j*16 + lr] = acc[i][j][r];
}

// K4: gate/prec layer1. fp16 2-product, BM=128 BN=256 BK=32, pre-swizzled W.
// NEW: single-barrier LDS double-buffer (write next tile to the other buffer,
// so ds_reads never depend on this iteration's ds_writes), 2-deep W register
// prefetch, s_setprio around the MFMA cluster. grid (4, 128).
__device__ __forceinline__ void gp_step(unsigned short (&RB)[8192],
    unsigned short (&WB)[8192], int kc, const unsigned short* wt, int soff,
    const float* arp0, const float* arp1, int rpB,
    uint4 (&wpf)[4], float4 (&a0)[2], float4 (&a1)[2], f32x4 (&acc)[2][16]){
  // stage W(kc+1) into the buffer NOT read this iteration
  if (kc < 63){
    #pragma unroll
    for (int i = 0; i < 4; i++) *(uint4*)(WB + soff + i*512) = wpf[i];
  }
  // split current A fp32 -> fp16 hi/lo
  f16x8 ah[2], al[2];
  #pragma unroll
  for (int i = 0; i < 2; i++){
    float av[8] = {a0[i].x,a0[i].y,a0[i].z,a0[i].w,a1[i].x,a1[i].y,a1[i].z,a1[i].w};
    #pragma unroll
    for (int e = 0; e < 8; e++){
      _Float16 h = (_Float16)av[e];
      ah[i][e] = h; al[i][e] = (_Float16)(av[e] - (float)h);
    }
  }
  // prefetch W(kc+2) into regs (2-deep pipeline) and A(kc+1)
  if (kc < 62){
    const unsigned short* wtn = wt + (size_t)(kc+2)*8192;
    #pragma unroll
    for (int i = 0; i < 4; i++) wpf[i] = *(const uint4*)(wtn + soff + i*512);
  }
  if (kc < 63){
    const int ko = (kc+1)*32;
    a0[0] = *(const float4*)(arp0 + ko); a1[0] = *(const float4*)(arp0 + ko + 4);
    a0[1] = *(const float4*)(arp1 + ko); a1[1] = *(const float4*)(arp1 + ko + 4);
  }
  __builtin_amdgcn_s_setprio(1);
  #pragma unroll
  for (int j = 0; j < 16; j++){
    f16x8 bh;
    __builtin_memcpy(&bh, RB + j*512 + rpB, 16);
    acc[0][j] = __builtin_amdgcn_mfma_f32_16x16x32_f16(ah[0], bh, acc[0][j], 0, 0, 0);
    acc[1][j] = __builtin_amdgcn_mfma_f32_16x16x32_f16(ah[1], bh, acc[1][j], 0, 0, 0);
    acc[0][j] = __builtin_amdgcn_mfma_f32_16x16x32_f16(al[0], bh, acc[0][j], 0, 0, 0);
    acc[1][j] = __builtin_amdgcn_mfma_f32_16x16x32_f16(al[1], bh, acc[1][j], 0, 0, 0);
  }
  __builtin_amdgcn_s_setprio(0);
  __syncthreads();   // reads of RB done; next iteration may overwrite RB
}

__global__ __launch_bounds__(256, 2) void k_gp(const float* __restrict__ A,
    const unsigned short* __restrict__ Wsw,
    const float* __restrict__ bg1, const float* __restrict__ bp1,
    const float* __restrict__ Wg2, const float* __restrict__ Wp2,
    float* __restrict__ z1, float* __restrict__ z2){
  const int nb = blockIdx.x;          // 0..3 (n0 = nb*256)
  const int m0 = blockIdx.y*128;
  const int tid = threadIdx.x;
  const int w = tid>>6, lane = tid&63, lr = lane&15, q = lane>>4;
  __shared__ __align__(16) unsigned short Bs0[8192];  // 16 KB
  __shared__ __align__(16) unsigned short Bs1[8192];  // 16 KB (double buffer)
  f32x4 acc[2][16] = {};

  const unsigned short* wt = Wsw + (size_t)nb*64*8192;
  const int soff = w*2048 + lane*8;                   // staging offset (halfs), +i*512
  const float* arp0 = A + (size_t)(m0 + w*32 + lr)*HH + q*8;
  const float* arp1 = A + (size_t)(m0 + w*32 + 16 + lr)*HH + q*8;
  const int rpB = lr*32 + ((q ^ ((lr & 3) ^ ((lr >> 2) & 3))) << 3);  // + j*512

  uint4 wpf[4];
  float4 a0[2], a1[2];
  // prologue: W(0) -> Bs0, W(1) -> regs, A(0) -> regs
  #pragma unroll
  for (int i = 0; i < 4; i++) wpf[i] = *(const uint4*)(wt + soff + i*512);
  a0[0] = *(const float4*)(arp0); a1[0] = *(const float4*)(arp0 + 4);
  a0[1] = *(const float4*)(arp1); a1[1] = *(const float4*)(arp1 + 4);
  #pragma unroll
  for (int i = 0; i < 4; i++) *(uint4*)(Bs0 + soff + i*512) = wpf[i];
  #pragma unroll
  for (int i = 0; i < 4; i++) wpf[i] = *(const uint4*)(wt + 8192 + soff + i*512);
  __syncthreads();

  for (int kc = 0; kc < 64; kc += 2){
    gp_step(Bs0, Bs1, kc,   wt, soff, arp0, arp1, rpB, wpf, a0, a1, acc);
    gp_step(Bs1, Bs0, kc+1, wt, soff, arp0, arp1, rpB, wpf, a0, a1, acc);
  }

  // epilogue: z[m] += sum_n relu(C[m,n] + b1[n]) * w2[n]   (register-light)
  const bool isP = (nb >= 2);
  const float* b1 = isP ? bp1 : bg1;
  const float* w2 = isP ? Wp2 : Wg2;
  float* zt = isP ? z2 : z1;
  const int nbl = nb*256 - (isP ? HQ : 0);
  float s[2][4] = {};
  #pragma unroll
  for (int j = 0; j < 16; j++){
    const int n = nbl + j*16 + lr;
    const float bb = b1[n], ww = w2[n];
    #pragma unroll
    for (int i = 0; i < 2; i++)
      #pragma unroll
      for (int r = 0; r < 4; r++)
        s[i][r] += fmaxf(acc[i][j][r] + bb, 0.f) * ww;
  }
  #pragma unroll
  for (int mk = 1; mk < 16; mk <<= 1)
    #pragma unroll
    for (int i = 0; i < 2; i++)
      #pragma unroll
      for (int r = 0; r < 4; r++)
        s[i][r] += __shfl_xor(s[i][r], mk);
  if (lr == 0){
    #pragma unroll
    for (int i = 0; i < 2; i++)
      #pragma unroll
      for (int r = 0; r < 4; r++)
        atomicAdd(&zt[m0 + w*32 + i*16 + q*4 + r], s[i][r]);
  }
}

// K5: per-t finalize — one wave per t, shuffle reductions (no barriers)
__global__ __launch_bounds__(256) void k_obs_fin(const float* __restrict__ obs_mean,
    const float* __restrict__ z1, const float* __restrict__ z2,
    const float* __restrict__ bg2, const float* __restrict__ bp2,
    float* __restrict__ out0, float* __restrict__ out3,
    float* __restrict__ obs_radii, unsigned short* __restrict__ obf){
  const int w = threadIdx.x >> 6, lane = threadIdx.x & 63;
  const int t = blockIdx.x*4 + w;
  float pm = 0.f;
  if (lane < TB){
    float a = z1[lane*TT + t] + bg2[0];
    float b = z2[lane*TT + t] + bp2[0];
    float gate = 1.f/(1.f + expf(-a));
    float sp = (b > 0.f) ? (b + log1pf(expf(-b))) : log1pf(expf(b));
    pm = gate * sp;
  }
  #pragma unroll
  for (int m = 1; m < 4; m <<= 1) pm += __shfl_xor(pm, m);
  pm = __shfl(pm, 0) * 0.25f;
  float4 x = *(const float4*)(obs_mean + (size_t)t*DD + lane*4);
  float ss = x.x*x.x + x.y*x.y + x.z*x.z + x.w*x.w;
  #pragma unroll
  for (int m = 1; m < 64; m <<= 1) ss += __shfl_xor(ss, m);
  const float nrm = sqrtf(ss);
  const float sc = pm / fmaxf(nrm, 1e-8f);
  float4 ob = {x.x*sc, x.y*sc, x.z*sc, x.w*sc};
  *(float4*)(out0 + (size_t)t*DD + lane*4) = ob;
  float s2 = ob.x*ob.x + ob.y*ob.y + ob.z*ob.z + ob.w*ob.w;
  #pragma unroll
  for (int m = 1; m < 64; m <<= 1) s2 += __shfl_xor(s2, m);
  const float r2 = sqrtf(s2);
  if (lane == 0){
    obs_radii[t] = r2;
    out3[t] = (r2 > 0.05f) ? 1.f : 0.f;
  }
  const float inv2 = 1.f / fmaxf(r2, 1e-8f);
  ushort4 o = {f2bf(ob.x*inv2), f2bf(ob.y*inv2), f2bf(ob.z*inv2), f2bf(ob.w*inv2)};
  *(ushort4*)(obf + (size_t)t*DD + lane*4) = o;
}

// K6: normalize beliefs -> bf16 angles
__global__ __launch_bounds__(256) void k_beliefs(const float* __restrict__ bel,
    unsigned short* __restrict__ bbf){
  const int n = (blockIdx.x*256 + threadIdx.x) >> 6;
  const int lane = threadIdx.x & 63;
  const float4 v = *(const float4*)(bel + (size_t)n*DD + lane*4);
  float s = v.x*v.x + v.y*v.y + v.z*v.z + v.w*v.w;
  #pragma unroll
  for (int m = 1; m < 64; m <<= 1) s += __shfl_xor(s, m);
  const float inv = 1.f / fmaxf(sqrtf(s), 1e-8f);
  ushort4 o;
  o.x = f2bf(v.x*inv); o.y = f2bf(v.y*inv); o.z = f2bf(v.z*inv); o.w = f2bf(v.w*inv);
  *(ushort4*)(bbf + (size_t)n*DD + lane*4) = o;
}

// K6b: any_active flag — parallel, ballot + one atomic per wave
__global__ __launch_bounds__(256) void k_any(const unsigned char* __restrict__ mask,
    int* __restrict__ flag){
  const int i = blockIdx.x*256 + threadIdx.x;
  const int any = (mask[i] != 0) ? 1 : 0;
  if (__ballot(any)){
    if ((threadIdx.x & 63) == 0) atomicOr(flag, 1);
  }
}

// K7: fused sims + masked max/argmax.
// NEW: no LDS staging at all — bbf slice (512 KB per n-split) is L1/L2-resident
// and reused across 32 t-blocks, so the global->reg->LDS->barrier round-trip was
// pure serialization (zero barriers now; occupancy VGPR-limited only).
// 1D grid of 1024 with bijective XCD-clustering: blocks with the same bid%8
// (same XCD under round-robin dispatch) share 4 n-split slices -> 2 MB hot/XCD L2.
__global__ __launch_bounds__(256, 4) void k_sims(const unsigned short* __restrict__ obf,
    const unsigned short* __restrict__ bbf, const unsigned char* __restrict__ mask,
    float* __restrict__ pmax, int* __restrict__ pidx){
  const int bid = blockIdx.x;                // 0..1023
  const int ns = (bid & 7)*4 + ((bid >> 3) & 3);   // n-split 0..31 (bijective with t0)
  const int t0 = (bid >> 5) * 128;
  const int nbase0 = ns * (NN/32);
  const int tid = threadIdx.x;
  const int w = tid >> 6, lane = tid & 63;
  const int lr = lane & 15, q = lane >> 4;
  bf16x8 afr[2][8];
  #pragma unroll
  for (int i = 0; i < 2; i++){
    const unsigned short* ap = obf + (size_t)(t0 + w*32 + i*16 + lr)*DD + q*8;
    #pragma unroll
    for (int ks = 0; ks < 8; ks++)
      afr[i][ks] = as_bf16x8(*(const uint4*)(ap + ks*32));
  }
  float vmax[2][4] = {{-INFINITY,-INFINITY,-INFINITY,-INFINITY},
                      {-INFINITY,-INFINITY,-INFINITY,-INFINITY}};
  int   vidx[2][4] = {{-1,-1,-1,-1},{-1,-1,-1,-1}};
  for (int it = 0; it < (NN/32)/64; it++){
    const int nb = nbase0 + it*64;
    #pragma unroll
    for (int sub = 0; sub < 4; sub++){
      const int row = nb + sub*16 + lr;
      const bool act = (mask[row] != 0);     // hoisted: latency hidden under MFMAs
      const unsigned short* bp = bbf + (size_t)row*DD + q*8;
      f32x4 acc[2] = {{0.f,0.f,0.f,0.f},{0.f,0.f,0.f,0.f}};
      #pragma unroll
      for (int kb = 0; kb < 2; kb++){        // 4 frags in flight: keeps VGPR <= 128
        bf16x8 bfr[4];
        #pragma unroll
        for (int ks = 0; ks < 4; ks++)
          bfr[ks] = as_bf16x8(*(const uint4*)(bp + (kb*4 + ks)*32));
        #pragma unroll
        for (int ks = 0; ks < 4; ks++){
          acc[0] = __builtin_amdgcn_mfma_f32_16x16x32_bf16(afr[0][kb*4+ks], bfr[ks], acc[0], 0, 0, 0);
          acc[1] = __builtin_amdgcn_mfma_f32_16x16x32_bf16(afr[1][kb*4+ks], bfr[ks], acc[1], 0, 0, 0);
        }
      }
      if (act){
        #pragma unroll
        for (int i = 0; i < 2; i++)
          #pragma unroll
          for (int r = 0; r < 4; r++)
            if (acc[i][r] > vmax[i][r]){ vmax[i][r] = acc[i][r]; vidx[i][r] = row; }
      }
    }
  }
  #pragma unroll
  for (int mk = 1; mk < 16; mk <<= 1){
    #pragma unroll
    for (int i = 0; i < 2; i++)
      #pragma unroll
      for (int r = 0; r < 4; r++){
        float om = __shfl_xor(vmax[i][r], mk);
        int   oi = __shfl_xor(vidx[i][r], mk);
        if (om > vmax[i][r] || (om == vmax[i][r] && (unsigned)oi < (unsigned)vidx[i][r])){
          vmax[i][r] = om; vidx[i][r] = oi;
        }
      }
  }
  if (lr == 0){
    #pragma unroll
    for (int i = 0; i < 2; i++)
      #pragma unroll
      for (int r = 0; r < 4; r++){
        const int t = t0 + w*32 + i*16 + q*4 + r;
        pmax[ns*TT + t] = vmax[i][r];
        pidx[ns*TT + t] = vidx[i][r];
      }
  }
}

// K8: combine n-splits + match logic
__global__ __launch_bounds__(256) void k_combine(const float* __restrict__ pmax,
    const int* __restrict__ pidx, const float* __restrict__ obs_radii,
    const int* __restrict__ flag, float* __restrict__ out1, float* __restrict__ out2){
  const int t = blockIdx.x*256 + threadIdx.x;
  float best = -INFINITY; int bi = -1;
  #pragma unroll
  for (int s = 0; s < 32; s++){
    float m = pmax[s*TT + t];
    if (m > best){ best = m; bi = pidx[s*TT + t]; }
  }
  const bool anyA = (flag[0] != 0);
  const bool mf = obs_radii[t] > 0.05f;
  const bool matched = mf && anyA && (best > 0.5f);
  out1[t] = matched ? best : 0.f;
  out2[t] = matched ? (float)bi : -1.f;
}

extern "C" void kernel_launch(void* const* d_in, const int* in_sizes, int n_in,
                              void* d_out, int out_size, void* d_ws, size_t ws_size,
                              hipStream_t stream) {
  const float* hidden = (const float*)d_in[0];
  const float* beliefs = (const float*)d_in[1];
  const unsigned char* amask = (const unsigned char*)d_in[2];
  const float* W_obs = (const float*)d_in[3];
  const float* W_g1 = (const float*)d_in[4];
  const float* b_g1 = (const float*)d_in[5];
  const float* W_g2 = (const float*)d_in[6];
  const float* b_g2 = (const float*)d_in[7];
  const float* W_p1 = (const float*)d_in[8];
  const float* b_p1 = (const float*)d_in[9];
  const float* W_p2 = (const float*)d_in[10];
  const float* b_p2 = (const float*)d_in[11];

  char* ws = (char*)d_ws;
  const size_t HMB_OFF  = 0;                 // 16777216
  const size_t WSW_OFF  = 16777216;          // 1024*2048*2 = 4194304 (swizzled)
  const size_t WOB_OFF  = 20971520;          // 1048576
  const size_t OM_OFF   = 22020096;          // 4194304
  const size_t Z1_OFF   = 26214400;          // 65536
  const size_t Z2_OFF   = 26279936;          // 65536
  const size_t FLAG_OFF = 26345472;          // 256  (contiguous with z1/z2 for memset)
  const size_t RAD_OFF  = 26345728;          // 16384
  const size_t OBF_OFF  = 26362112;          // 2097152
  const size_t BBF_OFF  = 28459264;          // 16777216
  const size_t PMAX_OFF = 45236480;          // 524288
  const size_t PIDX_OFF = 45760768;          // 524288    end ~46.3 MB

  unsigned short* hmb = (unsigned short*)(ws + HMB_OFF);
  unsigned short* Wsw = (unsigned short*)(ws + WSW_OFF);
  unsigned short* wob = (unsigned short*)(ws + WOB_OFF);
  float* om  = (float*)(ws + OM_OFF);
  float* z1  = (float*)(ws + Z1_OFF);
  float* z2  = (float*)(ws + Z2_OFF);
  int*   flg = (int*)(ws + FLAG_OFF);
  float* rad = (float*)(ws + RAD_OFF);
  unsigned short* obf = (unsigned short*)(ws + OBF_OFF);
  unsigned short* bbf = (unsigned short*)(ws + BBF_OFF);
  float* pmax = (float*)(ws + PMAX_OFF);
  int*   pidx = (int*)(ws + PIDX_OFF);

  float* out0 = (float*)d_out;            // [T,D] obs_beliefs
  float* out1 = out0 + (size_t)TT*DD;     // [T] sims_out
  float* out2 = out1 + TT;                // [T] slots
  float* out3 = out2 + TT;                // [T] meaningful

  hipMemsetAsync(ws + Z1_OFF, 0, 2*MM*sizeof(float) + 256, stream);  // z1,z2,flag

  k_mean    <<<TT*HH/4/256, 256, 0, stream>>>(hidden, hmb);
  k_cvt_w   <<<(1024*HH/8)/256, 256, 0, stream>>>(W_g1, W_p1, Wsw);
  k_cvt_wobs<<<(DD*HH/4)/256, 256, 0, stream>>>(W_obs, wob);
  k_obs     <<<dim3(DD/128, TT/128), 256, 0, stream>>>(hmb, wob, om);
  k_gp      <<<dim3(4, MM/128), 256, 0, stream>>>(hidden, Wsw, b_g1, b_p1,
                                                  W_g2, W_p2, z1, z2);
  k_obs_fin <<<TT/4, 256, 0, stream>>>(om, z1, z2, b_g2, b_p2, out0, out3, rad, obf);
  k_beliefs <<<NN/4, 256, 0, stream>>>(beliefs, bbf);
  k_any     <<<NN/256, 256, 0, stream>>>(amask, flg);
  k_sims    <<<1024, 256, 0, stream>>>(obf, bbf, amask, pmax, pidx);
  k_combine <<<TT/256, 256, 0, stream>>>(pmax, pidx, rad, flg, out1, out2);
}

// Round 2
// 609.989 us; speedup vs baseline: 1.2442x; 1.2442x over previous
//
#include <hip/hip_runtime.h>
#include <hip/hip_bf16.h>
#include <math.h>

#define TB 4
#define TT 4096
#define HH 2048
#define DD 256
#define NN 32768
#define HQ 512
#define MM (TB*TT)

typedef __attribute__((ext_vector_type(8))) short bf16x8;
typedef __attribute__((ext_vector_type(8))) _Float16 f16x8;
typedef __attribute__((ext_vector_type(4))) float f32x4;

__device__ inline unsigned short f2bf(float x){
  __hip_bfloat16 h = __float2bfloat16(x);
  return *reinterpret_cast<unsigned short*>(&h);
}

__device__ inline unsigned short f2h(float x){
  _Float16 h = (_Float16)x;
  unsigned short u; __builtin_memcpy(&u, &h, 2); return u;
}

__device__ inline bf16x8 as_bf16x8(uint4 u){ bf16x8 r; __builtin_memcpy(&r,&u,16); return r; }

// async global->LDS DMA, 16B per lane. LDS dest = uniform base + lane*16.
__device__ __forceinline__ void gload_lds16(const unsigned short* g, unsigned short* l){
  __builtin_amdgcn_global_load_lds(
      (const __attribute__((address_space(1))) unsigned int*)g,
      (__attribute__((address_space(3))) unsigned int*)l, 16, 0, 0);
}

// K1: batch-mean only (bf16 out)
__global__ __launch_bounds__(256) void k_mean(const float* __restrict__ h,
    unsigned short* __restrict__ hmb){
  const size_t i = (size_t)blockIdx.x*256 + threadIdx.x;   // float4 idx in [T*H/4]
  const size_t TH4 = (size_t)TT*HH/4;
  const float4* p = (const float4*)h;
  float4 v0 = p[i], v1 = p[i+TH4], v2 = p[i+2*TH4], v3 = p[i+3*TH4];
  float4 m;
  m.x = 0.25f*(v0.x+v1.x+v2.x+v3.x);
  m.y = 0.25f*(v0.y+v1.y+v2.y+v3.y);
  m.z = 0.25f*(v0.z+v1.z+v2.z+v3.z);
  m.w = 0.25f*(v0.w+v1.w+v2.w+v3.w);
  ushort4 o; o.x = f2bf(m.x); o.y = f2bf(m.y); o.z = f2bf(m.z); o.w = f2bf(m.w);
  *(ushort4*)(hmb + i*4) = o;
}

// K2: W_g1||W_p1 -> fp16, pre-swizzled tile-linear layout for k_gp.
__global__ __launch_bounds__(256) void k_cvt_w(const float* __restrict__ Wg1,
    const float* __restrict__ Wp1, unsigned short* __restrict__ Wsw){
  const int id = blockIdx.x*256 + threadIdx.x;       // 262144 8-half chunks
  const int n = id >> 8;                             // row 0..1023
  const int cg = id & 255;                           // chunk in row
  const int k = cg*8;
  const int kc = cg >> 2;
  const int c8 = cg & 3;
  const float* src = (n < HQ) ? (Wg1 + (size_t)n*HH + k) : (Wp1 + (size_t)(n-HQ)*HH + k);
  float4 v0 = *(const float4*)src;
  float4 v1 = *(const float4*)(src + 4);
  unsigned short o[8] = {f2h(v0.x),f2h(v0.y),f2h(v0.z),f2h(v0.w),
                         f2h(v1.x),f2h(v1.y),f2h(v1.z),f2h(v1.w)};
  const int nb = n >> 8, r = n & 255;
  const int s = (r & 3) ^ ((r >> 2) & 3);
  unsigned short* dst = Wsw + ((size_t)(nb*64 + kc))*8192 + r*32 + ((c8 ^ s) << 3);
  __builtin_memcpy(dst, o, 16);
}

// K2b: W_obs -> bf16 [256,2048]
__global__ __launch_bounds__(256) void k_cvt_wobs(const float* __restrict__ W,
    unsigned short* __restrict__ Wb){
  const int idx4 = blockIdx.x*256 + threadIdx.x;     // 131072 float4s
  float4 v = *(const float4*)(W + (size_t)idx4*4);
  ushort4 o; o.x = f2bf(v.x); o.y = f2bf(v.y); o.z = f2bf(v.z); o.w = f2bf(v.w);
  *(ushort4*)(Wb + (size_t)idx4*4) = o;
}

// K3: obs_mean = hmb @ wob^T  (bf16 MFMA, f32 out)  [4096,2048]x[256,2048]^T
__global__ __launch_bounds__(256) void k_obs(const unsigned short* __restrict__ A,
    const unsigned short* __restrict__ Bw, float* __restrict__ C){
  const int n0 = blockIdx.x*128, m0 = blockIdx.y*128;
  const int tid = threadIdx.x;
  const int w = tid>>6, lane = tid&63, lr = lane&15, q = lane>>4;
  __shared__ __align__(16) unsigned short Bs[128][40];
  f32x4 acc[2][8] = {};
  for (int k0 = 0; k0 < HH; k0 += 32){
    __syncthreads();
    #pragma unroll
    for (int ii = 0; ii < 2; ii++){
      int idx = tid + ii*256;
      int row = idx >> 2, c8 = (idx & 3)*8;
      *(uint4*)&Bs[row][c8] = *(const uint4*)(Bw + (size_t)(n0+row)*HH + k0 + c8);
    }
    bf16x8 a[2];
    #pragma unroll
    for (int i = 0; i < 2; i++)
      a[i] = as_bf16x8(*(const uint4*)(A + (size_t)(m0 + w*32 + i*16 + lr)*HH + k0 + q*8));
    __syncthreads();
    #pragma unroll
    for (int j = 0; j < 8; j++){
      bf16x8 b = as_bf16x8(*(const uint4*)&Bs[j*16 + lr][q*8]);
      #pragma unroll
      for (int i = 0; i < 2; i++)
        acc[i][j] = __builtin_amdgcn_mfma_f32_16x16x32_bf16(a[i], b, acc[i][j], 0, 0, 0);
    }
  }
  #pragma unroll
  for (int i = 0; i < 2; i++)
    #pragma unroll
    for (int j = 0; j < 8; j++)
      #pragma unroll
      for (int r = 0; r < 4; r++)
        C[(size_t)(m0 + w*32 + i*16 + q*4 + r)*DD + n0 + j*16 + lr] = acc[i][j][r];
}

// K4: gate/prec layer1. fp16 2-product, BM=128 BN=256 BK=32, pre-swizzled W.
// Single-barrier LDS double-buffer + 2-deep reg prefetch (round-1 structure).
// NEW: XCD-grouped 1D grid — the 4 nb-blocks sharing an A-panel (same m0) land
// on the SAME XCD so the 1MB fp32 panel is fetched into one L2, not four.
__device__ __forceinline__ void gp_step(unsigned short (&RB)[8192],
    unsigned short (&WB)[8192], int kc, const unsigned short* wt, int soff,
    const float* arp0, const float* arp1, int rpB,
    uint4 (&wpf)[4], float4 (&a0)[2], float4 (&a1)[2], f32x4 (&acc)[2][16]){
  if (kc < 63){
    #pragma unroll
    for (int i = 0; i < 4; i++) *(uint4*)(WB + soff + i*512) = wpf[i];
  }
  f16x8 ah[2], al[2];
  #pragma unroll
  for (int i = 0; i < 2; i++){
    float av[8] = {a0[i].x,a0[i].y,a0[i].z,a0[i].w,a1[i].x,a1[i].y,a1[i].z,a1[i].w};
    #pragma unroll
    for (int e = 0; e < 8; e++){
      _Float16 h = (_Float16)av[e];
      ah[i][e] = h; al[i][e] = (_Float16)(av[e] - (float)h);
    }
  }
  if (kc < 62){
    const unsigned short* wtn = wt + (size_t)(kc+2)*8192;
    #pragma unroll
    for (int i = 0; i < 4; i++) wpf[i] = *(const uint4*)(wtn + soff + i*512);
  }
  if (kc < 63){
    const int ko = (kc+1)*32;
    a0[0] = *(const float4*)(arp0 + ko); a1[0] = *(const float4*)(arp0 + ko + 4);
    a0[1] = *(const float4*)(arp1 + ko); a1[1] = *(const float4*)(arp1 + ko + 4);
  }
  __builtin_amdgcn_s_setprio(1);
  #pragma unroll
  for (int j = 0; j < 16; j++){
    f16x8 bh;
    __builtin_memcpy(&bh, RB + j*512 + rpB, 16);
    acc[0][j] = __builtin_amdgcn_mfma_f32_16x16x32_f16(ah[0], bh, acc[0][j], 0, 0, 0);
    acc[1][j] = __builtin_amdgcn_mfma_f32_16x16x32_f16(ah[1], bh, acc[1][j], 0, 0, 0);
    acc[0][j] = __builtin_amdgcn_mfma_f32_16x16x32_f16(al[0], bh, acc[0][j], 0, 0, 0);
    acc[1][j] = __builtin_amdgcn_mfma_f32_16x16x32_f16(al[1], bh, acc[1][j], 0, 0, 0);
  }
  __builtin_amdgcn_s_setprio(0);
  __syncthreads();
}

__global__ __launch_bounds__(256, 2) void k_gp(const float* __restrict__ A,
    const unsigned short* __restrict__ Wsw,
    const float* __restrict__ bg1, const float* __restrict__ bp1,
    const float* __restrict__ Wg2, const float* __restrict__ Wp2,
    float* __restrict__ z1, float* __restrict__ z2){
  // bijective XCD-grouping: bid = (my&7) + 8*(nb + 4*(my>>3))
  const int bid = blockIdx.x;
  const int nb = (bid >> 3) & 3;
  const int my = (bid & 7) + ((bid >> 5) << 3);
  const int m0 = my*128;
  const int tid = threadIdx.x;
  const int w = tid>>6, lane = tid&63, lr = lane&15, q = lane>>4;
  __shared__ __align__(16) unsigned short Bs0[8192];
  __shared__ __align__(16) unsigned short Bs1[8192];
  f32x4 acc[2][16] = {};

  const unsigned short* wt = Wsw + (size_t)nb*64*8192;
  const int soff = w*2048 + lane*8;
  const float* arp0 = A + (size_t)(m0 + w*32 + lr)*HH + q*8;
  const float* arp1 = A + (size_t)(m0 + w*32 + 16 + lr)*HH + q*8;
  const int rpB = lr*32 + ((q ^ ((lr & 3) ^ ((lr >> 2) & 3))) << 3);

  uint4 wpf[4];
  float4 a0[2], a1[2];
  #pragma unroll
  for (int i = 0; i < 4; i++) wpf[i] = *(const uint4*)(wt + soff + i*512);
  a0[0] = *(const float4*)(arp0); a1[0] = *(const float4*)(arp0 + 4);
  a0[1] = *(const float4*)(arp1); a1[1] = *(const float4*)(arp1 + 4);
  #pragma unroll
  for (int i = 0; i < 4; i++) *(uint4*)(Bs0 + soff + i*512) = wpf[i];
  #pragma unroll
  for (int i = 0; i < 4; i++) wpf[i] = *(const uint4*)(wt + 8192 + soff + i*512);
  __syncthreads();

  for (int kc = 0; kc < 64; kc += 2){
    gp_step(Bs0, Bs1, kc,   wt, soff, arp0, arp1, rpB, wpf, a0, a1, acc);
    gp_step(Bs1, Bs0, kc+1, wt, soff, arp0, arp1, rpB, wpf, a0, a1, acc);
  }

  const bool isP = (nb >= 2);
  const float* b1 = isP ? bp1 : bg1;
  const float* w2 = isP ? Wp2 : Wg2;
  float* zt = isP ? z2 : z1;
  const int nbl = nb*256 - (isP ? HQ : 0);
  float s[2][4] = {};
  #pragma unroll
  for (int j = 0; j < 16; j++){
    const int n = nbl + j*16 + lr;
    const float bb = b1[n], ww = w2[n];
    #pragma unroll
    for (int i = 0; i < 2; i++)
      #pragma unroll
      for (int r = 0; r < 4; r++)
        s[i][r] += fmaxf(acc[i][j][r] + bb, 0.f) * ww;
  }
  #pragma unroll
  for (int mk = 1; mk < 16; mk <<= 1)
    #pragma unroll
    for (int i = 0; i < 2; i++)
      #pragma unroll
      for (int r = 0; r < 4; r++)
        s[i][r] += __shfl_xor(s[i][r], mk);
  if (lr == 0){
    #pragma unroll
    for (int i = 0; i < 2; i++)
      #pragma unroll
      for (int r = 0; r < 4; r++)
        atomicAdd(&zt[m0 + w*32 + i*16 + q*4 + r], s[i][r]);
  }
}

// K5: per-t finalize — one wave per t, shuffle reductions (no barriers)
__global__ __launch_bounds__(256) void k_obs_fin(const float* __restrict__ obs_mean,
    const float* __restrict__ z1, const float* __restrict__ z2,
    const float* __restrict__ bg2, const float* __restrict__ bp2,
    float* __restrict__ out0, float* __restrict__ out3,
    float* __restrict__ obs_radii, unsigned short* __restrict__ obf){
  const int w = threadIdx.x >> 6, lane = threadIdx.x & 63;
  const int t = blockIdx.x*4 + w;
  float pm = 0.f;
  if (lane < TB){
    float a = z1[lane*TT + t] + bg2[0];
    float b = z2[lane*TT + t] + bp2[0];
    float gate = 1.f/(1.f + expf(-a));
    float sp = (b > 0.f) ? (b + log1pf(expf(-b))) : log1pf(expf(b));
    pm = gate * sp;
  }
  #pragma unroll
  for (int m = 1; m < 4; m <<= 1) pm += __shfl_xor(pm, m);
  pm = __shfl(pm, 0) * 0.25f;
  float4 x = *(const float4*)(obs_mean + (size_t)t*DD + lane*4);
  float ss = x.x*x.x + x.y*x.y + x.z*x.z + x.w*x.w;
  #pragma unroll
  for (int m = 1; m < 64; m <<= 1) ss += __shfl_xor(ss, m);
  const float nrm = sqrtf(ss);
  const float sc = pm / fmaxf(nrm, 1e-8f);
  float4 ob = {x.x*sc, x.y*sc, x.z*sc, x.w*sc};
  *(float4*)(out0 + (size_t)t*DD + lane*4) = ob;
  float s2 = ob.x*ob.x + ob.y*ob.y + ob.z*ob.z + ob.w*ob.w;
  #pragma unroll
  for (int m = 1; m < 64; m <<= 1) s2 += __shfl_xor(s2, m);
  const float r2 = sqrtf(s2);
  if (lane == 0){
    obs_radii[t] = r2;
    out3[t] = (r2 > 0.05f) ? 1.f : 0.f;
  }
  const float inv2 = 1.f / fmaxf(r2, 1e-8f);
  ushort4 o = {f2bf(ob.x*inv2), f2bf(ob.y*inv2), f2bf(ob.z*inv2), f2bf(ob.w*inv2)};
  *(ushort4*)(obf + (size_t)t*DD + lane*4) = o;
}

// K6: normalize beliefs -> bf16 angles
__global__ __launch_bounds__(256) void k_beliefs(const float* __restrict__ bel,
    unsigned short* __restrict__ bbf){
  const int n = (blockIdx.x*256 + threadIdx.x) >> 6;
  const int lane = threadIdx.x & 63;
  const float4 v = *(const float4*)(bel + (size_t)n*DD + lane*4);
  float s = v.x*v.x + v.y*v.y + v.z*v.z + v.w*v.w;
  #pragma unroll
  for (int m = 1; m < 64; m <<= 1) s += __shfl_xor(s, m);
  const float inv = 1.f / fmaxf(sqrtf(s), 1e-8f);
  ushort4 o;
  o.x = f2bf(v.x*inv); o.y = f2bf(v.y*inv); o.z = f2bf(v.z*inv); o.w = f2bf(v.w*inv);
  *(ushort4*)(bbf + (size_t)n*DD + lane*4) = o;
}

// K6b: any_active flag — parallel, ballot + one atomic per wave
__global__ __launch_bounds__(256) void k_any(const unsigned char* __restrict__ mask,
    int* __restrict__ flag){
  const int i = blockIdx.x*256 + threadIdx.x;
  const int any = (mask[i] != 0) ? 1 : 0;
  if (__ballot(any)){
    if ((threadIdx.x & 63) == 0) atomicOr(flag, 1);
  }
}

// K7: fused sims + masked max/argmax. LDS-staged (restored from round-0) but
// upgraded to async 2-phase: global_load_lds DMA (16B) into a double-buffered
// 2x32KB tile, ONE barrier per tile, next-tile loads issued BEFORE the MFMA
// block so the barrier's vmcnt(0) drain finds them complete.
// Swizzle (rule #21, both-sides): LDS slot p of row r holds natural chunk
// p^(r&31) — achieved by inverse-swizzling the per-lane GLOBAL source while
// the LDS dest stays linear; reads use p=(q+4ks)^(r&31) as in round-0.
__global__ __launch_bounds__(256) void k_sims(const unsigned short* __restrict__ obf,
    const unsigned short* __restrict__ bbf, const unsigned char* __restrict__ mask,
    float* __restrict__ pmax, int* __restrict__ pidx){
  const int t0 = blockIdx.x * 128;
  const int ns = blockIdx.y;                 // 0..31
  const int nbase0 = ns * (NN/32);
  const int tid = threadIdx.x;
  const int w = tid >> 6, lane = tid & 63;
  const int lr = lane & 15, q = lane >> 4;
  __shared__ __align__(16) unsigned short bt[2][64*256];
  const int srow = lane >> 5;                // staging: lane covers row rb+srow
  const int sp   = lane & 31;                // slot within row

  // prologue: issue DMA for tile 0 first (starts earliest)
  #pragma unroll
  for (int i = 0; i < 8; i++){
    const int rb = (i*4 + w)*2;
    const int row = rb + srow;
    const unsigned short* src = bbf + (size_t)(nbase0 + row)*DD + ((sp ^ (row & 31)) << 3);
    gload_lds16(src, &bt[0][(i*4 + w)*512]);
  }
  // A fragments into registers (latency overlaps the DMA)
  bf16x8 afr[2][8];
  #pragma unroll
  for (int i = 0; i < 2; i++){
    const unsigned short* ap = obf + (size_t)(t0 + w*32 + i*16 + lr)*DD + q*8;
    #pragma unroll
    for (int ks = 0; ks < 8; ks++)
      afr[i][ks] = as_bf16x8(*(const uint4*)(ap + ks*32));
  }
  __syncthreads();   // drains vmcnt: tile 0 + afr ready

  float vmax[2][4] = {{-INFINITY,-INFINITY,-INFINITY,-INFINITY},
                      {-INFINITY,-INFINITY,-INFINITY,-INFINITY}};
  int   vidx[2][4] = {{-1,-1,-1,-1},{-1,-1,-1,-1}};
  int cur = 0;
  for (int it = 0; it < (NN/32)/64; it++){
    const int nb = nbase0 + it*64;
    if (it < (NN/32)/64 - 1){                // stage tile(it+1) into the other buffer
      const int nbn = nb + 64;
      #pragma unroll
      for (int i = 0; i < 8; i++){
        const int rb = (i*4 + w)*2;
        const int row = rb + srow;
        const unsigned short* src = bbf + (size_t)(nbn + row)*DD + ((sp ^ (row & 31)) << 3);
        gload_lds16(src, &bt[cur^1][(i*4 + w)*512]);
      }
    }
    const unsigned short* btc = bt[cur];
    #pragma unroll
    for (int sub = 0; sub < 4; sub++){
      const int rowi = sub*16 + lr;
      const bool act = (mask[nb + rowi] != 0);   // tiny, L1-hot; used post-MFMA
      const unsigned short* bp = btc + rowi*256;
      const int rx = rowi & 31;
      f32x4 acc[2] = {{0.f,0.f,0.f,0.f},{0.f,0.f,0.f,0.f}};
      #pragma unroll
      for (int ks = 0; ks < 8; ks++){
        const int p = (q + ks*4) ^ rx;
        bf16x8 bfr = as_bf16x8(*(const uint4*)(bp + p*8));
        acc[0] = __builtin_amdgcn_mfma_f32_16x16x32_bf16(afr[0][ks], bfr, acc[0], 0, 0, 0);
        acc[1] = __builtin_amdgcn_mfma_f32_16x16x32_bf16(afr[1][ks], bfr, acc[1], 0, 0, 0);
      }
      if (act){
        const int n = nb + rowi;
        #pragma unroll
        for (int i = 0; i < 2; i++)
          #pragma unroll
          for (int r = 0; r < 4; r++)
            if (acc[i][r] > vmax[i][r]){ vmax[i][r] = acc[i][r]; vidx[i][r] = n; }
      }
    }
    __syncthreads();   // reads of bt[cur] done AND tile(it+1) DMA drained
    cur ^= 1;
  }
  #pragma unroll
  for (int mk = 1; mk < 16; mk <<= 1){
    #pragma unroll
    for (int i = 0; i < 2; i++)
      #pragma unroll
      for (int r = 0; r < 4; r++){
        float om = __shfl_xor(vmax[i][r], mk);
        int   oi = __shfl_xor(vidx[i][r], mk);
        if (om > vmax[i][r] || (om == vmax[i][r] && (unsigned)oi < (unsigned)vidx[i][r])){
          vmax[i][r] = om; vidx[i][r] = oi;
        }
      }
  }
  if (lr == 0){
    #pragma unroll
    for (int i = 0; i < 2; i++)
      #pragma unroll
      for (int r = 0; r < 4; r++){
        const int t = t0 + w*32 + i*16 + q*4 + r;
        pmax[ns*TT + t] = vmax[i][r];
        pidx[ns*TT + t] = vidx[i][r];
      }
  }
}

// K8: combine n-splits + match logic
__global__ __launch_bounds__(256) void k_combine(const float* __restrict__ pmax,
    const int* __restrict__ pidx, const float* __restrict__ obs_radii,
    const int* __restrict__ flag, float* __restrict__ out1, float* __restrict__ out2){
  const int t = blockIdx.x*256 + threadIdx.x;
  float best = -INFINITY; int bi = -1;
  #pragma unroll
  for (int s = 0; s < 32; s++){
    float m = pmax[s*TT + t];
    if (m > best){ best = m; bi = pidx[s*TT + t]; }
  }
  const bool anyA = (flag[0] != 0);
  const bool mf = obs_radii[t] > 0.05f;
  const bool matched = mf && anyA && (best > 0.5f);
  out1[t] = matched ? best : 0.f;
  out2[t] = matched ? (float)bi : -1.f;
}

extern "C" void kernel_launch(void* const* d_in, const int* in_sizes, int n_in,
                              void* d_out, int out_size, void* d_ws, size_t ws_size,
                              hipStream_t stream) {
  const float* hidden = (const float*)d_in[0];
  const float* beliefs = (const float*)d_in[1];
  const unsigned char* amask = (const unsigned char*)d_in[2];
  const float* W_obs = (const float*)d_in[3];
  const float* W_g1 = (const float*)d_in[4];
  const float* b_g1 = (const float*)d_in[5];
  const float* W_g2 = (const float*)d_in[6];
  const float* b_g2 = (const float*)d_in[7];
  const float* W_p1 = (const float*)d_in[8];
  const float* b_p1 = (const float*)d_in[9];
  const float* W_p2 = (const float*)d_in[10];
  const float* b_p2 = (const float*)d_in[11];

  char* ws = (char*)d_ws;
  const size_t HMB_OFF  = 0;                 // 16777216
  const size_t WSW_OFF  = 16777216;          // 4194304 (swizzled)
  const size_t WOB_OFF  = 20971520;          // 1048576
  const size_t OM_OFF   = 22020096;          // 4194304
  const size_t Z1_OFF   = 26214400;          // 65536
  const size_t Z2_OFF   = 26279936;          // 65536
  const size_t FLAG_OFF = 26345472;          // 256
  const size_t RAD_OFF  = 26345728;          // 16384
  const size_t OBF_OFF  = 26362112;          // 2097152
  const size_t BBF_OFF  = 28459264;          // 16777216
  const size_t PMAX_OFF = 45236480;          // 524288
  const size_t PIDX_OFF = 45760768;          // 524288    end ~46.3 MB

  unsigned short* hmb = (unsigned short*)(ws + HMB_OFF);
  unsigned short* Wsw = (unsigned short*)(ws + WSW_OFF);
  unsigned short* wob = (unsigned short*)(ws + WOB_OFF);
  float* om  = (float*)(ws + OM_OFF);
  float* z1  = (float*)(ws + Z1_OFF);
  float* z2  = (float*)(ws + Z2_OFF);
  int*   flg = (int*)(ws + FLAG_OFF);
  float* rad = (float*)(ws + RAD_OFF);
  unsigned short* obf = (unsigned short*)(ws + OBF_OFF);
  unsigned short* bbf = (unsigned short*)(ws + BBF_OFF);
  float* pmax = (float*)(ws + PMAX_OFF);
  int*   pidx = (int*)(ws + PIDX_OFF);

  float* out0 = (float*)d_out;            // [T,D] obs_beliefs
  float* out1 = out0 + (size_t)TT*DD;     // [T] sims_out
  float* out2 = out1 + TT;                // [T] slots
  float* out3 = out2 + TT;                // [T] meaningful

  hipMemsetAsync(ws + Z1_OFF, 0, 2*MM*sizeof(float) + 256, stream);  // z1,z2,flag

  k_mean    <<<TT*HH/4/256, 256, 0, stream>>>(hidden, hmb);
  k_cvt_w   <<<(1024*HH/8)/256, 256, 0, stream>>>(W_g1, W_p1, Wsw);
  k_cvt_wobs<<<(DD*HH/4)/256, 256, 0, stream>>>(W_obs, wob);
  k_obs     <<<dim3(DD/128, TT/128), 256, 0, stream>>>(hmb, wob, om);
  k_gp      <<<512, 256, 0, stream>>>(hidden, Wsw, b_g1, b_p1, W_g2, W_p2, z1, z2);
  k_obs_fin <<<TT/4, 256, 0, stream>>>(om, z1, z2, b_g2, b_p2, out0, out3, rad, obf);
  k_beliefs <<<NN/4, 256, 0, stream>>>(beliefs, bbf);
  k_any     <<<NN/256, 256, 0, stream>>>(amask, flg);
  k_sims    <<<dim3(TT/128, 32), 256, 0, stream>>>(obf, bbf, amask, pmax, pidx);
  k_combine <<<TT/256, 256, 0, stream>>>(pmax, pidx, rad, flg, out1, out2);
}

// Round 3
// 605.611 us; speedup vs baseline: 1.2532x; 1.0072x over previous
//
#include <hip/hip_runtime.h>
#include <hip/hip_bf16.h>
#include <math.h>

#define TB 4
#define TT 4096
#define HH 2048
#define DD 256
#define NN 32768
#define HQ 512
#define MM (TB*TT)

typedef __attribute__((ext_vector_type(8))) short bf16x8;
typedef __attribute__((ext_vector_type(8))) _Float16 f16x8;
typedef __attribute__((ext_vector_type(4))) float f32x4;

__device__ inline unsigned short f2bf(float x){
  __hip_bfloat16 h = __float2bfloat16(x);
  return *reinterpret_cast<unsigned short*>(&h);
}

__device__ inline unsigned short f2h(float x){
  _Float16 h = (_Float16)x;
  unsigned short u; __builtin_memcpy(&u, &h, 2); return u;
}

__device__ inline bf16x8 as_bf16x8(uint4 u){ bf16x8 r; __builtin_memcpy(&r,&u,16); return r; }

// async global->LDS DMA, 16B per lane. LDS dest = uniform base + lane*16.
__device__ __forceinline__ void gload_lds16(const unsigned short* g, unsigned short* l){
  __builtin_amdgcn_global_load_lds(
      (const __attribute__((address_space(1))) unsigned int*)g,
      (__attribute__((address_space(3))) unsigned int*)l, 16, 0, 0);
}

// K1: batch-mean only (bf16 out)
__global__ __launch_bounds__(256) void k_mean(const float* __restrict__ h,
    unsigned short* __restrict__ hmb){
  const size_t i = (size_t)blockIdx.x*256 + threadIdx.x;   // float4 idx in [T*H/4]
  const size_t TH4 = (size_t)TT*HH/4;
  const float4* p = (const float4*)h;
  float4 v0 = p[i], v1 = p[i+TH4], v2 = p[i+2*TH4], v3 = p[i+3*TH4];
  float4 m;
  m.x = 0.25f*(v0.x+v1.x+v2.x+v3.x);
  m.y = 0.25f*(v0.y+v1.y+v2.y+v3.y);
  m.z = 0.25f*(v0.z+v1.z+v2.z+v3.z);
  m.w = 0.25f*(v0.w+v1.w+v2.w+v3.w);
  ushort4 o; o.x = f2bf(m.x); o.y = f2bf(m.y); o.z = f2bf(m.z); o.w = f2bf(m.w);
  *(ushort4*)(hmb + i*4) = o;
}

// K2: W_g1||W_p1 -> fp16, pre-swizzled tile-linear layout for k_gp.
__global__ __launch_bounds__(256) void k_cvt_w(const float* __restrict__ Wg1,
    const float* __restrict__ Wp1, unsigned short* __restrict__ Wsw){
  const int id = blockIdx.x*256 + threadIdx.x;       // 262144 8-half chunks
  const int n = id >> 8;                             // row 0..1023
  const int cg = id & 255;                           // chunk in row
  const int k = cg*8;
  const int kc = cg >> 2;
  const int c8 = cg & 3;
  const float* src = (n < HQ) ? (Wg1 + (size_t)n*HH + k) : (Wp1 + (size_t)(n-HQ)*HH + k);
  float4 v0 = *(const float4*)src;
  float4 v1 = *(const float4*)(src + 4);
  unsigned short o[8] = {f2h(v0.x),f2h(v0.y),f2h(v0.z),f2h(v0.w),
                         f2h(v1.x),f2h(v1.y),f2h(v1.z),f2h(v1.w)};
  const int nb = n >> 8, r = n & 255;
  const int s = (r & 3) ^ ((r >> 2) & 3);
  unsigned short* dst = Wsw + ((size_t)(nb*64 + kc))*8192 + r*32 + ((c8 ^ s) << 3);
  __builtin_memcpy(dst, o, 16);
}

// K2b: W_obs -> bf16 [256,2048]
__global__ __launch_bounds__(256) void k_cvt_wobs(const float* __restrict__ W,
    unsigned short* __restrict__ Wb){
  const int idx4 = blockIdx.x*256 + threadIdx.x;     // 131072 float4s
  float4 v = *(const float4*)(W + (size_t)idx4*4);
  ushort4 o; o.x = f2bf(v.x); o.y = f2bf(v.y); o.z = f2bf(v.z); o.w = f2bf(v.w);
  *(ushort4*)(Wb + (size_t)idx4*4) = o;
}

// K3: obs_mean = hmb @ wob^T  (bf16 MFMA, f32 out)  [4096,2048]x[256,2048]^T
__global__ __launch_bounds__(256) void k_obs(const unsigned short* __restrict__ A,
    const unsigned short* __restrict__ Bw, float* __restrict__ C){
  const int n0 = blockIdx.x*128, m0 = blockIdx.y*128;
  const int tid = threadIdx.x;
  const int w = tid>>6, lane = tid&63, lr = lane&15, q = lane>>4;
  __shared__ __align__(16) unsigned short Bs[128][40];
  f32x4 acc[2][8] = {};
  for (int k0 = 0; k0 < HH; k0 += 32){
    __syncthreads();
    #pragma unroll
    for (int ii = 0; ii < 2; ii++){
      int idx = tid + ii*256;
      int row = idx >> 2, c8 = (idx & 3)*8;
      *(uint4*)&Bs[row][c8] = *(const uint4*)(Bw + (size_t)(n0+row)*HH + k0 + c8);
    }
    bf16x8 a[2];
    #pragma unroll
    for (int i = 0; i < 2; i++)
      a[i] = as_bf16x8(*(const uint4*)(A + (size_t)(m0 + w*32 + i*16 + lr)*HH + k0 + q*8));
    __syncthreads();
    #pragma unroll
    for (int j = 0; j < 8; j++){
      bf16x8 b = as_bf16x8(*(const uint4*)&Bs[j*16 + lr][q*8]);
      #pragma unroll
      for (int i = 0; i < 2; i++)
        acc[i][j] = __builtin_amdgcn_mfma_f32_16x16x32_bf16(a[i], b, acc[i][j], 0, 0, 0);
    }
  }
  #pragma unroll
  for (int i = 0; i < 2; i++)
    #pragma unroll
    for (int j = 0; j < 8; j++)
      #pragma unroll
      for (int r = 0; r < 4; r++)
        C[(size_t)(m0 + w*32 + i*16 + q*4 + r)*DD + n0 + j*16 + lr] = acc[i][j][r];
}

// K4: gate/prec layer1. fp16 2-product, BM=128 BN=256 BK=32, pre-swizzled W.
// Double-buffered LDS, 2-deep reg prefetch, XCD-grouped grid.
// NEW (T4): raw s_barrier with lgkmcnt(0)-ONLY drain — __syncthreads() was
// draining vmcnt(0) every step, killing the 8-load prefetch pipeline. Global
// prefetch loads now stay in flight across the barrier (counted waits are
// auto-inserted by the compiler at first register use, one full MFMA-block
// later). LDS write-visibility (the only cross-wave hazard) is preserved by
// the explicit lgkmcnt(0) before s_barrier.
__device__ __forceinline__ void gp_step(unsigned short (&RB)[8192],
    unsigned short (&WB)[8192], int kc, const unsigned short* wt, int soff,
    const float* arp0, const float* arp1, int rpB,
    uint4 (&wpf)[4], float4 (&a0)[2], float4 (&a1)[2], f32x4 (&acc)[2][16]){
  if (kc < 63){
    #pragma unroll
    for (int i = 0; i < 4; i++) *(uint4*)(WB + soff + i*512) = wpf[i];
  }
  f16x8 ah[2], al[2];
  #pragma unroll
  for (int i = 0; i < 2; i++){
    float av[8] = {a0[i].x,a0[i].y,a0[i].z,a0[i].w,a1[i].x,a1[i].y,a1[i].z,a1[i].w};
    #pragma unroll
    for (int e = 0; e < 8; e++){
      _Float16 h = (_Float16)av[e];
      ah[i][e] = h; al[i][e] = (_Float16)(av[e] - (float)h);
    }
  }
  if (kc < 62){
    const unsigned short* wtn = wt + (size_t)(kc+2)*8192;
    #pragma unroll
    for (int i = 0; i < 4; i++) wpf[i] = *(const uint4*)(wtn + soff + i*512);
  }
  if (kc < 63){
    const int ko = (kc+1)*32;
    a0[0] = *(const float4*)(arp0 + ko); a1[0] = *(const float4*)(arp0 + ko + 4);
    a0[1] = *(const float4*)(arp1 + ko); a1[1] = *(const float4*)(arp1 + ko + 4);
  }
  __builtin_amdgcn_s_setprio(1);
  #pragma unroll
  for (int j = 0; j < 16; j++){
    f16x8 bh;
    __builtin_memcpy(&bh, RB + j*512 + rpB, 16);
    acc[0][j] = __builtin_amdgcn_mfma_f32_16x16x32_f16(ah[0], bh, acc[0][j], 0, 0, 0);
    acc[1][j] = __builtin_amdgcn_mfma_f32_16x16x32_f16(ah[1], bh, acc[1][j], 0, 0, 0);
    acc[0][j] = __builtin_amdgcn_mfma_f32_16x16x32_f16(al[0], bh, acc[0][j], 0, 0, 0);
    acc[1][j] = __builtin_amdgcn_mfma_f32_16x16x32_f16(al[1], bh, acc[1][j], 0, 0, 0);
  }
  __builtin_amdgcn_s_setprio(0);
  asm volatile("s_waitcnt lgkmcnt(0)" ::: "memory");  // LDS ops drained; vmcnt NOT
  __builtin_amdgcn_s_barrier();
}

__global__ __launch_bounds__(256, 2) void k_gp(const float* __restrict__ A,
    const unsigned short* __restrict__ Wsw,
    const float* __restrict__ bg1, const float* __restrict__ bp1,
    const float* __restrict__ Wg2, const float* __restrict__ Wp2,
    float* __restrict__ z1, float* __restrict__ z2){
  // bijective XCD-grouping: bid = (my&7) + 8*(nb + 4*(my>>3))
  const int bid = blockIdx.x;
  const int nb = (bid >> 3) & 3;
  const int my = (bid & 7) + ((bid >> 5) << 3);
  const int m0 = my*128;
  const int tid = threadIdx.x;
  const int w = tid>>6, lane = tid&63, lr = lane&15, q = lane>>4;
  __shared__ __align__(16) unsigned short Bs0[8192];
  __shared__ __align__(16) unsigned short Bs1[8192];
  f32x4 acc[2][16] = {};

  const unsigned short* wt = Wsw + (size_t)nb*64*8192;
  const int soff = w*2048 + lane*8;
  const float* arp0 = A + (size_t)(m0 + w*32 + lr)*HH + q*8;
  const float* arp1 = A + (size_t)(m0 + w*32 + 16 + lr)*HH + q*8;
  const int rpB = lr*32 + ((q ^ ((lr & 3) ^ ((lr >> 2) & 3))) << 3);

  uint4 wpf[4];
  float4 a0[2], a1[2];
  #pragma unroll
  for (int i = 0; i < 4; i++) wpf[i] = *(const uint4*)(wt + soff + i*512);
  a0[0] = *(const float4*)(arp0); a1[0] = *(const float4*)(arp0 + 4);
  a0[1] = *(const float4*)(arp1); a1[1] = *(const float4*)(arp1 + 4);
  #pragma unroll
  for (int i = 0; i < 4; i++) *(uint4*)(Bs0 + soff + i*512) = wpf[i];
  #pragma unroll
  for (int i = 0; i < 4; i++) wpf[i] = *(const uint4*)(wt + 8192 + soff + i*512);
  __syncthreads();

  for (int kc = 0; kc < 64; kc += 2){
    gp_step(Bs0, Bs1, kc,   wt, soff, arp0, arp1, rpB, wpf, a0, a1, acc);
    gp_step(Bs1, Bs0, kc+1, wt, soff, arp0, arp1, rpB, wpf, a0, a1, acc);
  }

  const bool isP = (nb >= 2);
  const float* b1 = isP ? bp1 : bg1;
  const float* w2 = isP ? Wp2 : Wg2;
  float* zt = isP ? z2 : z1;
  const int nbl = nb*256 - (isP ? HQ : 0);
  float s[2][4] = {};
  #pragma unroll
  for (int j = 0; j < 16; j++){
    const int n = nbl + j*16 + lr;
    const float bb = b1[n], ww = w2[n];
    #pragma unroll
    for (int i = 0; i < 2; i++)
      #pragma unroll
      for (int r = 0; r < 4; r++)
        s[i][r] += fmaxf(acc[i][j][r] + bb, 0.f) * ww;
  }
  #pragma unroll
  for (int mk = 1; mk < 16; mk <<= 1)
    #pragma unroll
    for (int i = 0; i < 2; i++)
      #pragma unroll
      for (int r = 0; r < 4; r++)
        s[i][r] += __shfl_xor(s[i][r], mk);
  if (lr == 0){
    #pragma unroll
    for (int i = 0; i < 2; i++)
      #pragma unroll
      for (int r = 0; r < 4; r++)
        atomicAdd(&zt[m0 + w*32 + i*16 + q*4 + r], s[i][r]);
  }
}

// K5: per-t finalize — one wave per t, shuffle reductions (no barriers)
__global__ __launch_bounds__(256) void k_obs_fin(const float* __restrict__ obs_mean,
    const float* __restrict__ z1, const float* __restrict__ z2,
    const float* __restrict__ bg2, const float* __restrict__ bp2,
    float* __restrict__ out0, float* __restrict__ out3,
    float* __restrict__ obs_radii, unsigned short* __restrict__ obf){
  const int w = threadIdx.x >> 6, lane = threadIdx.x & 63;
  const int t = blockIdx.x*4 + w;
  float pm = 0.f;
  if (lane < TB){
    float a = z1[lane*TT + t] + bg2[0];
    float b = z2[lane*TT + t] + bp2[0];
    float gate = 1.f/(1.f + expf(-a));
    float sp = (b > 0.f) ? (b + log1pf(expf(-b))) : log1pf(expf(b));
    pm = gate * sp;
  }
  #pragma unroll
  for (int m = 1; m < 4; m <<= 1) pm += __shfl_xor(pm, m);
  pm = __shfl(pm, 0) * 0.25f;
  float4 x = *(const float4*)(obs_mean + (size_t)t*DD + lane*4);
  float ss = x.x*x.x + x.y*x.y + x.z*x.z + x.w*x.w;
  #pragma unroll
  for (int m = 1; m < 64; m <<= 1) ss += __shfl_xor(ss, m);
  const float nrm = sqrtf(ss);
  const float sc = pm / fmaxf(nrm, 1e-8f);
  float4 ob = {x.x*sc, x.y*sc, x.z*sc, x.w*sc};
  *(float4*)(out0 + (size_t)t*DD + lane*4) = ob;
  float s2 = ob.x*ob.x + ob.y*ob.y + ob.z*ob.z + ob.w*ob.w;
  #pragma unroll
  for (int m = 1; m < 64; m <<= 1) s2 += __shfl_xor(s2, m);
  const float r2 = sqrtf(s2);
  if (lane == 0){
    obs_radii[t] = r2;
    out3[t] = (r2 > 0.05f) ? 1.f : 0.f;
  }
  const float inv2 = 1.f / fmaxf(r2, 1e-8f);
  ushort4 o = {f2bf(ob.x*inv2), f2bf(ob.y*inv2), f2bf(ob.z*inv2), f2bf(ob.w*inv2)};
  *(ushort4*)(obf + (size_t)t*DD + lane*4) = o;
}

// K6: normalize beliefs -> bf16 angles
__global__ __launch_bounds__(256) void k_beliefs(const float* __restrict__ bel,
    unsigned short* __restrict__ bbf){
  const int n = (blockIdx.x*256 + threadIdx.x) >> 6;
  const int lane = threadIdx.x & 63;
  const float4 v = *(const float4*)(bel + (size_t)n*DD + lane*4);
  float s = v.x*v.x + v.y*v.y + v.z*v.z + v.w*v.w;
  #pragma unroll
  for (int m = 1; m < 64; m <<= 1) s += __shfl_xor(s, m);
  const float inv = 1.f / fmaxf(sqrtf(s), 1e-8f);
  ushort4 o;
  o.x = f2bf(v.x*inv); o.y = f2bf(v.y*inv); o.z = f2bf(v.z*inv); o.w = f2bf(v.w*inv);
  *(ushort4*)(bbf + (size_t)n*DD + lane*4) = o;
}

// K6b: any_active flag — parallel, ballot + one atomic per wave
__global__ __launch_bounds__(256) void k_any(const unsigned char* __restrict__ mask,
    int* __restrict__ flag){
  const int i = blockIdx.x*256 + threadIdx.x;
  const int any = (mask[i] != 0) ? 1 : 0;
  if (__ballot(any)){
    if ((threadIdx.x & 63) == 0) atomicOr(flag, 1);
  }
}

// K7: fused sims + masked max/argmax. Async 2-phase gload_lds double-buffer,
// one barrier per tile (round-2 structure).
// NEW: XCD-grouped 1D grid — xcd = ns&7, so each XCD's L2 holds exactly its
// 4 bbf slices (2 MB) + obf (2 MB) resident, instead of streaming all 16 MB
// of bbf through every XCD's 4 MB L2.
__global__ __launch_bounds__(256) void k_sims(const unsigned short* __restrict__ obf,
    const unsigned short* __restrict__ bbf, const unsigned char* __restrict__ mask,
    float* __restrict__ pmax, int* __restrict__ pidx){
  const int bid = blockIdx.x;                // 0..1023
  const int rest = bid >> 3;
  const int ns = (bid & 7) + ((rest >> 5) << 3);   // 0..31; xcd = ns&7
  const int t0 = (rest & 31) * 128;
  const int nbase0 = ns * (NN/32);
  const int tid = threadIdx.x;
  const int w = tid >> 6, lane = tid & 63;
  const int lr = lane & 15, q = lane >> 4;
  __shared__ __align__(16) unsigned short bt[2][64*256];
  const int srow = lane >> 5;                // staging: lane covers row rb+srow
  const int sp   = lane & 31;                // slot within row

  // prologue: issue DMA for tile 0 first (starts earliest)
  #pragma unroll
  for (int i = 0; i < 8; i++){
    const int rb = (i*4 + w)*2;
    const int row = rb + srow;
    const unsigned short* src = bbf + (size_t)(nbase0 + row)*DD + ((sp ^ (row & 31)) << 3);
    gload_lds16(src, &bt[0][(i*4 + w)*512]);
  }
  // A fragments into registers (latency overlaps the DMA)
  bf16x8 afr[2][8];
  #pragma unroll
  for (int i = 0; i < 2; i++){
    const unsigned short* ap = obf + (size_t)(t0 + w*32 + i*16 + lr)*DD + q*8;
    #pragma unroll
    for (int ks = 0; ks < 8; ks++)
      afr[i][ks] = as_bf16x8(*(const uint4*)(ap + ks*32));
  }
  __syncthreads();   // drains vmcnt: tile 0 + afr ready

  float vmax[2][4] = {{-INFINITY,-INFINITY,-INFINITY,-INFINITY},
                      {-INFINITY,-INFINITY,-INFINITY,-INFINITY}};
  int   vidx[2][4] = {{-1,-1,-1,-1},{-1,-1,-1,-1}};
  int cur = 0;
  for (int it = 0; it < (NN/32)/64; it++){
    const int nb = nbase0 + it*64;
    if (it < (NN/32)/64 - 1){                // stage tile(it+1) into the other buffer
      const int nbn = nb + 64;
      #pragma unroll
      for (int i = 0; i < 8; i++){
        const int rb = (i*4 + w)*2;
        const int row = rb + srow;
        const unsigned short* src = bbf + (size_t)(nbn + row)*DD + ((sp ^ (row & 31)) << 3);
        gload_lds16(src, &bt[cur^1][(i*4 + w)*512]);
      }
    }
    const unsigned short* btc = bt[cur];
    #pragma unroll
    for (int sub = 0; sub < 4; sub++){
      const int rowi = sub*16 + lr;
      const bool act = (mask[nb + rowi] != 0);   // tiny, L1-hot; used post-MFMA
      const unsigned short* bp = btc + rowi*256;
      const int rx = rowi & 31;
      f32x4 acc[2] = {{0.f,0.f,0.f,0.f},{0.f,0.f,0.f,0.f}};
      #pragma unroll
      for (int ks = 0; ks < 8; ks++){
        const int p = (q + ks*4) ^ rx;
        bf16x8 bfr = as_bf16x8(*(const uint4*)(bp + p*8));
        acc[0] = __builtin_amdgcn_mfma_f32_16x16x32_bf16(afr[0][ks], bfr, acc[0], 0, 0, 0);
        acc[1] = __builtin_amdgcn_mfma_f32_16x16x32_bf16(afr[1][ks], bfr, acc[1], 0, 0, 0);
      }
      if (act){
        const int n = nb + rowi;
        #pragma unroll
        for (int i = 0; i < 2; i++)
          #pragma unroll
          for (int r = 0; r < 4; r++)
            if (acc[i][r] > vmax[i][r]){ vmax[i][r] = acc[i][r]; vidx[i][r] = n; }
      }
    }
    __syncthreads();   // reads of bt[cur] done AND tile(it+1) DMA drained
    cur ^= 1;
  }
  #pragma unroll
  for (int mk = 1; mk < 16; mk <<= 1){
    #pragma unroll
    for (int i = 0; i < 2; i++)
      #pragma unroll
      for (int r = 0; r < 4; r++){
        float om = __shfl_xor(vmax[i][r], mk);
        int   oi = __shfl_xor(vidx[i][r], mk);
        if (om > vmax[i][r] || (om == vmax[i][r] && (unsigned)oi < (unsigned)vidx[i][r])){
          vmax[i][r] = om; vidx[i][r] = oi;
        }
      }
  }
  if (lr == 0){
    #pragma unroll
    for (int i = 0; i < 2; i++)
      #pragma unroll
      for (int r = 0; r < 4; r++){
        const int t = t0 + w*32 + i*16 + q*4 + r;
        pmax[ns*TT + t] = vmax[i][r];
        pidx[ns*TT + t] = vidx[i][r];
      }
  }
}

// K8: combine n-splits + match logic
__global__ __launch_bounds__(256) void k_combine(const float* __restrict__ pmax,
    const int* __restrict__ pidx, const float* __restrict__ obs_radii,
    const int* __restrict__ flag, float* __restrict__ out1, float* __restrict__ out2){
  const int t = blockIdx.x*256 + threadIdx.x;
  float best = -INFINITY; int bi = -1;
  #pragma unroll
  for (int s = 0; s < 32; s++){
    float m = pmax[s*TT + t];
    if (m > best){ best = m; bi = pidx[s*TT + t]; }
  }
  const bool anyA = (flag[0] != 0);
  const bool mf = obs_radii[t] > 0.05f;
  const bool matched = mf && anyA && (best > 0.5f);
  out1[t] = matched ? best : 0.f;
  out2[t] = matched ? (float)bi : -1.f;
}

extern "C" void kernel_launch(void* const* d_in, const int* in_sizes, int n_in,
                              void* d_out, int out_size, void* d_ws, size_t ws_size,
                              hipStream_t stream) {
  const float* hidden = (const float*)d_in[0];
  const float* beliefs = (const float*)d_in[1];
  const unsigned char* amask = (const unsigned char*)d_in[2];
  const float* W_obs = (const float*)d_in[3];
  const float* W_g1 = (const float*)d_in[4];
  const float* b_g1 = (const float*)d_in[5];
  const float* W_g2 = (const float*)d_in[6];
  const float* b_g2 = (const float*)d_in[7];
  const float* W_p1 = (const float*)d_in[8];
  const float* b_p1 = (const float*)d_in[9];
  const float* W_p2 = (const float*)d_in[10];
  const float* b_p2 = (const float*)d_in[11];

  char* ws = (char*)d_ws;
  const size_t HMB_OFF  = 0;                 // 16777216
  const size_t WSW_OFF  = 16777216;          // 4194304 (swizzled)
  const size_t WOB_OFF  = 20971520;          // 1048576
  const size_t OM_OFF   = 22020096;          // 4194304
  const size_t Z1_OFF   = 26214400;          // 65536
  const size_t Z2_OFF   = 26279936;          // 65536
  const size_t FLAG_OFF = 26345472;          // 256
  const size_t RAD_OFF  = 26345728;          // 16384
  const size_t OBF_OFF  = 26362112;          // 2097152
  const size_t BBF_OFF  = 28459264;          // 16777216
  const size_t PMAX_OFF = 45236480;          // 524288
  const size_t PIDX_OFF = 45760768;          // 524288    end ~46.3 MB

  unsigned short* hmb = (unsigned short*)(ws + HMB_OFF);
  unsigned short* Wsw = (unsigned short*)(ws + WSW_OFF);
  unsigned short* wob = (unsigned short*)(ws + WOB_OFF);
  float* om  = (float*)(ws + OM_OFF);
  float* z1  = (float*)(ws + Z1_OFF);
  float* z2  = (float*)(ws + Z2_OFF);
  int*   flg = (int*)(ws + FLAG_OFF);
  float* rad = (float*)(ws + RAD_OFF);
  unsigned short* obf = (unsigned short*)(ws + OBF_OFF);
  unsigned short* bbf = (unsigned short*)(ws + BBF_OFF);
  float* pmax = (float*)(ws + PMAX_OFF);
  int*   pidx = (int*)(ws + PIDX_OFF);

  float* out0 = (float*)d_out;            // [T,D] obs_beliefs
  float* out1 = out0 + (size_t)TT*DD;     // [T] sims_out
  float* out2 = out1 + TT;                // [T] slots
  float* out3 = out2 + TT;                // [T] meaningful

  hipMemsetAsync(ws + Z1_OFF, 0, 2*MM*sizeof(float) + 256, stream);  // z1,z2,flag

  k_mean    <<<TT*HH/4/256, 256, 0, stream>>>(hidden, hmb);
  k_cvt_w   <<<(1024*HH/8)/256, 256, 0, stream>>>(W_g1, W_p1, Wsw);
  k_cvt_wobs<<<(DD*HH/4)/256, 256, 0, stream>>>(W_obs, wob);
  k_obs     <<<dim3(DD/128, TT/128), 256, 0, stream>>>(hmb, wob, om);
  k_gp      <<<512, 256, 0, stream>>>(hidden, Wsw, b_g1, b_p1, W_g2, W_p2, z1, z2);
  k_obs_fin <<<TT/4, 256, 0, stream>>>(om, z1, z2, b_g2, b_p2, out0, out3, rad, obf);
  k_beliefs <<<NN/4, 256, 0, stream>>>(beliefs, bbf);
  k_any     <<<NN/256, 256, 0, stream>>>(amask, flg);
  k_sims    <<<1024, 256, 0, stream>>>(obf, bbf, amask, pmax, pidx);
  k_combine <<<TT/256, 256, 0, stream>>>(pmax, pidx, rad, flg, out1, out2);
}

// Round 4
// 511.258 us; speedup vs baseline: 1.4845x; 1.1846x over previous
//
#include <hip/hip_runtime.h>
#include <hip/hip_bf16.h>
#include <math.h>

#define TB 4
#define TT 4096
#define HH 2048
#define DD 256
#define NN 32768
#define HQ 512
#define MM (TB*TT)

typedef __attribute__((ext_vector_type(8))) short bf16x8;
typedef __attribute__((ext_vector_type(8))) _Float16 f16x8;
typedef __attribute__((ext_vector_type(4))) float f32x4;

__device__ inline unsigned short f2bf(float x){
  __hip_bfloat16 h = __float2bfloat16(x);
  return *reinterpret_cast<unsigned short*>(&h);
}

__device__ inline unsigned short f2h(float x){
  _Float16 h = (_Float16)x;
  unsigned short u; __builtin_memcpy(&u, &h, 2); return u;
}

__device__ inline bf16x8 as_bf16x8(uint4 u){ bf16x8 r; __builtin_memcpy(&r,&u,16); return r; }

// async global->LDS DMA, 16B per lane. LDS dest = wave-uniform base + lane*16.
__device__ __forceinline__ void gload_ldsv(const void* g, void* l){
  __builtin_amdgcn_global_load_lds(
      (const __attribute__((address_space(1))) unsigned int*)g,
      (__attribute__((address_space(3))) unsigned int*)l, 16, 0, 0);
}

// K1: batch-mean only (bf16 out)
__global__ __launch_bounds__(256) void k_mean(const float* __restrict__ h,
    unsigned short* __restrict__ hmb){
  const size_t i = (size_t)blockIdx.x*256 + threadIdx.x;   // float4 idx in [T*H/4]
  const size_t TH4 = (size_t)TT*HH/4;
  const float4* p = (const float4*)h;
  float4 v0 = p[i], v1 = p[i+TH4], v2 = p[i+2*TH4], v3 = p[i+3*TH4];
  float4 m;
  m.x = 0.25f*(v0.x+v1.x+v2.x+v3.x);
  m.y = 0.25f*(v0.y+v1.y+v2.y+v3.y);
  m.z = 0.25f*(v0.z+v1.z+v2.z+v3.z);
  m.w = 0.25f*(v0.w+v1.w+v2.w+v3.w);
  ushort4 o; o.x = f2bf(m.x); o.y = f2bf(m.y); o.z = f2bf(m.z); o.w = f2bf(m.w);
  *(ushort4*)(hmb + i*4) = o;
}

// K2: W_g1||W_p1 -> fp16, pre-swizzled tile-linear layout for k_gp.
__global__ __launch_bounds__(256) void k_cvt_w(const float* __restrict__ Wg1,
    const float* __restrict__ Wp1, unsigned short* __restrict__ Wsw){
  const int id = blockIdx.x*256 + threadIdx.x;       // 262144 8-half chunks
  const int n = id >> 8;                             // row 0..1023
  const int cg = id & 255;                           // chunk in row
  const int k = cg*8;
  const int kc = cg >> 2;
  const int c8 = cg & 3;
  const float* src = (n < HQ) ? (Wg1 + (size_t)n*HH + k) : (Wp1 + (size_t)(n-HQ)*HH + k);
  float4 v0 = *(const float4*)src;
  float4 v1 = *(const float4*)(src + 4);
  unsigned short o[8] = {f2h(v0.x),f2h(v0.y),f2h(v0.z),f2h(v0.w),
                         f2h(v1.x),f2h(v1.y),f2h(v1.z),f2h(v1.w)};
  const int nb = n >> 8, r = n & 255;
  const int s = (r & 3) ^ ((r >> 2) & 3);
  unsigned short* dst = Wsw + ((size_t)(nb*64 + kc))*8192 + r*32 + ((c8 ^ s) << 3);
  __builtin_memcpy(dst, o, 16);
}

// K2b: W_obs -> bf16 [256,2048]
__global__ __launch_bounds__(256) void k_cvt_wobs(const float* __restrict__ W,
    unsigned short* __restrict__ Wb){
  const int idx4 = blockIdx.x*256 + threadIdx.x;     // 131072 float4s
  float4 v = *(const float4*)(W + (size_t)idx4*4);
  ushort4 o; o.x = f2bf(v.x); o.y = f2bf(v.y); o.z = f2bf(v.z); o.w = f2bf(v.w);
  *(ushort4*)(Wb + (size_t)idx4*4) = o;
}

// K3: obs_mean = hmb @ wob^T  (bf16 MFMA, f32 out)  [4096,2048]x[256,2048]^T
__global__ __launch_bounds__(256) void k_obs(const unsigned short* __restrict__ A,
    const unsigned short* __restrict__ Bw, float* __restrict__ C){
  const int n0 = blockIdx.x*128, m0 = blockIdx.y*128;
  const int tid = threadIdx.x;
  const int w = tid>>6, lane = tid&63, lr = lane&15, q = lane>>4;
  __shared__ __align__(16) unsigned short Bs[128][40];
  f32x4 acc[2][8] = {};
  for (int k0 = 0; k0 < HH; k0 += 32){
    __syncthreads();
    #pragma unroll
    for (int ii = 0; ii < 2; ii++){
      int idx = tid + ii*256;
      int row = idx >> 2, c8 = (idx & 3)*8;
      *(uint4*)&Bs[row][c8] = *(const uint4*)(Bw + (size_t)(n0+row)*HH + k0 + c8);
    }
    bf16x8 a[2];
    #pragma unroll
    for (int i = 0; i < 2; i++)
      a[i] = as_bf16x8(*(const uint4*)(A + (size_t)(m0 + w*32 + i*16 + lr)*HH + k0 + q*8));
    __syncthreads();
    #pragma unroll
    for (int j = 0; j < 8; j++){
      bf16x8 b = as_bf16x8(*(const uint4*)&Bs[j*16 + lr][q*8]);
      #pragma unroll
      for (int i = 0; i < 2; i++)
        acc[i][j] = __builtin_amdgcn_mfma_f32_16x16x32_bf16(a[i], b, acc[i][j], 0, 0, 0);
    }
  }
  #pragma unroll
  for (int i = 0; i < 2; i++)
    #pragma unroll
    for (int j = 0; j < 8; j++)
      #pragma unroll
      for (int r = 0; r < 4; r++)
        C[(size_t)(m0 + w*32 + i*16 + q*4 + r)*DD + n0 + j*16 + lr] = acc[i][j][r];
}

// K4: gate/prec layer1. fp16 2-product, BM=128 BN=256 BK=32.
// NEW (full-DMA template, proven on k_sims): BOTH operands staged via
// global_load_lds into double buffers; issue tile(t+1) DMA at step top, then
// convert+MFMA on tile(t), then ONE __syncthreads (its vmcnt(0) drain finds
// the DMAs landed — they had the whole compute block to cover HBM latency).
// This removes A's HBM loads from the wave's register dependency chain, which
// r1-r3 showed was the untouched stall (1-deep reg prefetch consumed at the
// top of the next step at 2 waves/SIMD = no cover).
// W: DMA with linear dest reproduces the pre-swizzled tile byte-for-byte
// (old code copied global->LDS at identical offsets). A: [128][32] f32 tile,
// 16B chunks XOR-swizzled via the GLOBAL source (rule #21), read back with
// the matching XOR: slot s of row r holds chunk s^(r&7).
__global__ __launch_bounds__(256, 2) void k_gp(const float* __restrict__ A,
    const unsigned short* __restrict__ Wsw,
    const float* __restrict__ bg1, const float* __restrict__ bp1,
    const float* __restrict__ Wg2, const float* __restrict__ Wp2,
    float* __restrict__ z1, float* __restrict__ z2){
  // bijective XCD-grouping: bid = (my&7) + 8*(nb + 4*(my>>3))
  const int bid = blockIdx.x;
  const int nb = (bid >> 3) & 3;
  const int my = (bid & 7) + ((bid >> 5) << 3);
  const int m0 = my*128;
  const int tid = threadIdx.x;
  const int w = tid>>6, lane = tid&63, lr = lane&15, q = lane>>4;
  __shared__ __align__(16) unsigned short Ws[2][8192];   // 2 x 16 KB W tiles
  __shared__ __align__(16) float As[2][4096];            // 2 x 16 KB A tiles
  f32x4 acc[2][16] = {};

  const unsigned short* wt = Wsw + (size_t)nb*64*8192 + w*2048 + lane*8;
  const int rpB = lr*32 + ((q ^ ((lr & 3) ^ ((lr >> 2) & 3))) << 3);
  // A staging geometry: instr i covers tile-rows w*32+i*8 .. +7;
  // lane -> row w*32+i*8+(lane>>3), LDS slot (lane&7), global chunk (lane&7)^(lane>>3)
  const int sr8 = lane >> 3;
  const int sc  = (lane & 7) ^ sr8;
  const float* asrc = A + (size_t)(m0 + w*32 + sr8)*HH + sc*4;

  // prologue: stage tile 0
  #pragma unroll
  for (int i = 0; i < 4; i++){
    gload_ldsv(wt + i*512, &Ws[0][w*2048 + i*512]);
    gload_ldsv(asrc + (size_t)i*8*HH, &As[0][(w*32 + i*8)*32]);
  }
  __syncthreads();

  for (int t = 0; t < 64; t++){
    const int cur = t & 1;
    if (t < 63){
      #pragma unroll
      for (int i = 0; i < 4; i++){
        gload_ldsv(wt + (size_t)(t+1)*8192 + i*512, &Ws[cur^1][w*2048 + i*512]);
        gload_ldsv(asrc + (size_t)i*8*HH + (t+1)*32, &As[cur^1][(w*32 + i*8)*32]);
      }
    }
    // convert A (from LDS) -> fp16 hi/lo
    const float* At = As[cur];
    f16x8 ah[2], al[2];
    #pragma unroll
    for (int i = 0; i < 2; i++){
      const int tr = w*32 + i*16 + lr;
      const int px = lr & 7;                   // = tr&7
      float4 fa = *(const float4*)&At[tr*32 + (((2*q)   ^ px) << 2)];
      float4 fb = *(const float4*)&At[tr*32 + (((2*q+1) ^ px) << 2)];
      float av[8] = {fa.x,fa.y,fa.z,fa.w, fb.x,fb.y,fb.z,fb.w};
      #pragma unroll
      for (int e = 0; e < 8; e++){
        _Float16 h = (_Float16)av[e];
        ah[i][e] = h; al[i][e] = (_Float16)(av[e] - (float)h);
      }
    }
    const unsigned short* Wc = Ws[cur];
    __builtin_amdgcn_s_setprio(1);
    #pragma unroll
    for (int j = 0; j < 16; j++){
      f16x8 bh;
      __builtin_memcpy(&bh, Wc + j*512 + rpB, 16);
      acc[0][j] = __builtin_amdgcn_mfma_f32_16x16x32_f16(ah[0], bh, acc[0][j], 0, 0, 0);
      acc[1][j] = __builtin_amdgcn_mfma_f32_16x16x32_f16(ah[1], bh, acc[1][j], 0, 0, 0);
      acc[0][j] = __builtin_amdgcn_mfma_f32_16x16x32_f16(al[0], bh, acc[0][j], 0, 0, 0);
      acc[1][j] = __builtin_amdgcn_mfma_f32_16x16x32_f16(al[1], bh, acc[1][j], 0, 0, 0);
    }
    __builtin_amdgcn_s_setprio(0);
    __syncthreads();   // vmcnt(0)+lgkmcnt(0)+barrier: tile(t+1) landed, tile(t) reads done
  }

  // epilogue: z[m] += sum_n relu(C[m,n] + b1[n]) * w2[n]   (register-light)
  const bool isP = (nb >= 2);
  const float* b1 = isP ? bp1 : bg1;
  const float* w2 = isP ? Wp2 : Wg2;
  float* zt = isP ? z2 : z1;
  const int nbl = nb*256 - (isP ? HQ : 0);
  float s[2][4] = {};
  #pragma unroll
  for (int j = 0; j < 16; j++){
    const int n = nbl + j*16 + lr;
    const float bb = b1[n], ww = w2[n];
    #pragma unroll
    for (int i = 0; i < 2; i++)
      #pragma unroll
      for (int r = 0; r < 4; r++)
        s[i][r] += fmaxf(acc[i][j][r] + bb, 0.f) * ww;
  }
  #pragma unroll
  for (int mk = 1; mk < 16; mk <<= 1)
    #pragma unroll
    for (int i = 0; i < 2; i++)
      #pragma unroll
      for (int r = 0; r < 4; r++)
        s[i][r] += __shfl_xor(s[i][r], mk);
  if (lr == 0){
    #pragma unroll
    for (int i = 0; i < 2; i++)
      #pragma unroll
      for (int r = 0; r < 4; r++)
        atomicAdd(&zt[m0 + w*32 + i*16 + q*4 + r], s[i][r]);
  }
}

// K5: per-t finalize — one wave per t, shuffle reductions (no barriers)
__global__ __launch_bounds__(256) void k_obs_fin(const float* __restrict__ obs_mean,
    const float* __restrict__ z1, const float* __restrict__ z2,
    const float* __restrict__ bg2, const float* __restrict__ bp2,
    float* __restrict__ out0, float* __restrict__ out3,
    float* __restrict__ obs_radii, unsigned short* __restrict__ obf){
  const int w = threadIdx.x >> 6, lane = threadIdx.x & 63;
  const int t = blockIdx.x*4 + w;
  float pm = 0.f;
  if (lane < TB){
    float a = z1[lane*TT + t] + bg2[0];
    float b = z2[lane*TT + t] + bp2[0];
    float gate = 1.f/(1.f + expf(-a));
    float sp = (b > 0.f) ? (b + log1pf(expf(-b))) : log1pf(expf(b));
    pm = gate * sp;
  }
  #pragma unroll
  for (int m = 1; m < 4; m <<= 1) pm += __shfl_xor(pm, m);
  pm = __shfl(pm, 0) * 0.25f;
  float4 x = *(const float4*)(obs_mean + (size_t)t*DD + lane*4);
  float ss = x.x*x.x + x.y*x.y + x.z*x.z + x.w*x.w;
  #pragma unroll
  for (int m = 1; m < 64; m <<= 1) ss += __shfl_xor(ss, m);
  const float nrm = sqrtf(ss);
  const float sc = pm / fmaxf(nrm, 1e-8f);
  float4 ob = {x.x*sc, x.y*sc, x.z*sc, x.w*sc};
  *(float4*)(out0 + (size_t)t*DD + lane*4) = ob;
  float s2 = ob.x*ob.x + ob.y*ob.y + ob.z*ob.z + ob.w*ob.w;
  #pragma unroll
  for (int m = 1; m < 64; m <<= 1) s2 += __shfl_xor(s2, m);
  const float r2 = sqrtf(s2);
  if (lane == 0){
    obs_radii[t] = r2;
    out3[t] = (r2 > 0.05f) ? 1.f : 0.f;
  }
  const float inv2 = 1.f / fmaxf(r2, 1e-8f);
  ushort4 o = {f2bf(ob.x*inv2), f2bf(ob.y*inv2), f2bf(ob.z*inv2), f2bf(ob.w*inv2)};
  *(ushort4*)(obf + (size_t)t*DD + lane*4) = o;
}

// K6: normalize beliefs -> bf16 angles
__global__ __launch_bounds__(256) void k_beliefs(const float* __restrict__ bel,
    unsigned short* __restrict__ bbf){
  const int n = (blockIdx.x*256 + threadIdx.x) >> 6;
  const int lane = threadIdx.x & 63;
  const float4 v = *(const float4*)(bel + (size_t)n*DD + lane*4);
  float s = v.x*v.x + v.y*v.y + v.z*v.z + v.w*v.w;
  #pragma unroll
  for (int m = 1; m < 64; m <<= 1) s += __shfl_xor(s, m);
  const float inv = 1.f / fmaxf(sqrtf(s), 1e-8f);
  ushort4 o;
  o.x = f2bf(v.x*inv); o.y = f2bf(v.y*inv); o.z = f2bf(v.z*inv); o.w = f2bf(v.w*inv);
  *(ushort4*)(bbf + (size_t)n*DD + lane*4) = o;
}

// K6b: any_active flag — parallel, ballot + one atomic per wave
__global__ __launch_bounds__(256) void k_any(const unsigned char* __restrict__ mask,
    int* __restrict__ flag){
  const int i = blockIdx.x*256 + threadIdx.x;
  const int any = (mask[i] != 0) ? 1 : 0;
  if (__ballot(any)){
    if ((threadIdx.x & 63) == 0) atomicOr(flag, 1);
  }
}

// K7: fused sims + masked max/argmax. Async 2-phase gload_lds double-buffer,
// one barrier per tile; XCD-grouped grid (xcd = ns&7: each XCD's L2 holds its
// 4 bbf slices + obf resident).
__global__ __launch_bounds__(256) void k_sims(const unsigned short* __restrict__ obf,
    const unsigned short* __restrict__ bbf, const unsigned char* __restrict__ mask,
    float* __restrict__ pmax, int* __restrict__ pidx){
  const int bid = blockIdx.x;                // 0..1023
  const int rest = bid >> 3;
  const int ns = (bid & 7) + ((rest >> 5) << 3);   // 0..31; xcd = ns&7
  const int t0 = (rest & 31) * 128;
  const int nbase0 = ns * (NN/32);
  const int tid = threadIdx.x;
  const int w = tid >> 6, lane = tid & 63;
  const int lr = lane & 15, q = lane >> 4;
  __shared__ __align__(16) unsigned short bt[2][64*256];
  const int srow = lane >> 5;                // staging: lane covers row rb+srow
  const int sp   = lane & 31;                // slot within row

  // prologue: issue DMA for tile 0 first (starts earliest)
  #pragma unroll
  for (int i = 0; i < 8; i++){
    const int rb = (i*4 + w)*2;
    const int row = rb + srow;
    const unsigned short* src = bbf + (size_t)(nbase0 + row)*DD + ((sp ^ (row & 31)) << 3);
    gload_ldsv(src, &bt[0][(i*4 + w)*512]);
  }
  // A fragments into registers (latency overlaps the DMA)
  bf16x8 afr[2][8];
  #pragma unroll
  for (int i = 0; i < 2; i++){
    const unsigned short* ap = obf + (size_t)(t0 + w*32 + i*16 + lr)*DD + q*8;
    #pragma unroll
    for (int ks = 0; ks < 8; ks++)
      afr[i][ks] = as_bf16x8(*(const uint4*)(ap + ks*32));
  }
  __syncthreads();   // drains vmcnt: tile 0 + afr ready

  float vmax[2][4] = {{-INFINITY,-INFINITY,-INFINITY,-INFINITY},
                      {-INFINITY,-INFINITY,-INFINITY,-INFINITY}};
  int   vidx[2][4] = {{-1,-1,-1,-1},{-1,-1,-1,-1}};
  int cur = 0;
  for (int it = 0; it < (NN/32)/64; it++){
    const int nb = nbase0 + it*64;
    if (it < (NN/32)/64 - 1){                // stage tile(it+1) into the other buffer
      const int nbn = nb + 64;
      #pragma unroll
      for (int i = 0; i < 8; i++){
        const int rb = (i*4 + w)*2;
        const int row = rb + srow;
        const unsigned short* src = bbf + (size_t)(nbn + row)*DD + ((sp ^ (row & 31)) << 3);
        gload_ldsv(src, &bt[cur^1][(i*4 + w)*512]);
      }
    }
    const unsigned short* btc = bt[cur];
    #pragma unroll
    for (int sub = 0; sub < 4; sub++){
      const int rowi = sub*16 + lr;
      const bool act = (mask[nb + rowi] != 0);   // tiny, L1-hot; used post-MFMA
      const unsigned short* bp = btc + rowi*256;
      const int rx = rowi & 31;
      f32x4 acc[2] = {{0.f,0.f,0.f,0.f},{0.f,0.f,0.f,0.f}};
      #pragma unroll
      for (int ks = 0; ks < 8; ks++){
        const int p = (q + ks*4) ^ rx;
        bf16x8 bfr = as_bf16x8(*(const uint4*)(bp + p*8));
        acc[0] = __builtin_amdgcn_mfma_f32_16x16x32_bf16(afr[0][ks], bfr, acc[0], 0, 0, 0);
        acc[1] = __builtin_amdgcn_mfma_f32_16x16x32_bf16(afr[1][ks], bfr, acc[1], 0, 0, 0);
      }
      if (act){
        const int n = nb + rowi;
        #pragma unroll
        for (int i = 0; i < 2; i++)
          #pragma unroll
          for (int r = 0; r < 4; r++)
            if (acc[i][r] > vmax[i][r]){ vmax[i][r] = acc[i][r]; vidx[i][r] = n; }
      }
    }
    __syncthreads();   // reads of bt[cur] done AND tile(it+1) DMA drained
    cur ^= 1;
  }
  #pragma unroll
  for (int mk = 1; mk < 16; mk <<= 1){
    #pragma unroll
    for (int i = 0; i < 2; i++)
      #pragma unroll
      for (int r = 0; r < 4; r++){
        float om = __shfl_xor(vmax[i][r], mk);
        int   oi = __shfl_xor(vidx[i][r], mk);
        if (om > vmax[i][r] || (om == vmax[i][r] && (unsigned)oi < (unsigned)vidx[i][r])){
          vmax[i][r] = om; vidx[i][r] = oi;
        }
      }
  }
  if (lr == 0){
    #pragma unroll
    for (int i = 0; i < 2; i++)
      #pragma unroll
      for (int r = 0; r < 4; r++){
        const int t = t0 + w*32 + i*16 + q*4 + r;
        pmax[ns*TT + t] = vmax[i][r];
        pidx[ns*TT + t] = vidx[i][r];
      }
  }
}

// K8: combine n-splits + match logic
__global__ __launch_bounds__(256) void k_combine(const float* __restrict__ pmax,
    const int* __restrict__ pidx, const float* __restrict__ obs_radii,
    const int* __restrict__ flag, float* __restrict__ out1, float* __restrict__ out2){
  const int t = blockIdx.x*256 + threadIdx.x;
  float best = -INFINITY; int bi = -1;
  #pragma unroll
  for (int s = 0; s < 32; s++){
    float m = pmax[s*TT + t];
    if (m > best){ best = m; bi = pidx[s*TT + t]; }
  }
  const bool anyA = (flag[0] != 0);
  const bool mf = obs_radii[t] > 0.05f;
  const bool matched = mf && anyA && (best > 0.5f);
  out1[t] = matched ? best : 0.f;
  out2[t] = matched ? (float)bi : -1.f;
}

extern "C" void kernel_launch(void* const* d_in, const int* in_sizes, int n_in,
                              void* d_out, int out_size, void* d_ws, size_t ws_size,
                              hipStream_t stream) {
  const float* hidden = (const float*)d_in[0];
  const float* beliefs = (const float*)d_in[1];
  const unsigned char* amask = (const unsigned char*)d_in[2];
  const float* W_obs = (const float*)d_in[3];
  const float* W_g1 = (const float*)d_in[4];
  const float* b_g1 = (const float*)d_in[5];
  const float* W_g2 = (const float*)d_in[6];
  const float* b_g2 = (const float*)d_in[7];
  const float* W_p1 = (const float*)d_in[8];
  const float* b_p1 = (const float*)d_in[9];
  const float* W_p2 = (const float*)d_in[10];
  const float* b_p2 = (const float*)d_in[11];

  char* ws = (char*)d_ws;
  const size_t HMB_OFF  = 0;                 // 16777216
  const size_t WSW_OFF  = 16777216;          // 4194304 (swizzled)
  const size_t WOB_OFF  = 20971520;          // 1048576
  const size_t OM_OFF   = 22020096;          // 4194304
  const size_t Z1_OFF   = 26214400;          // 65536
  const size_t Z2_OFF   = 26279936;          // 65536
  const size_t FLAG_OFF = 26345472;          // 256
  const size_t RAD_OFF  = 26345728;          // 16384
  const size_t OBF_OFF  = 26362112;          // 2097152
  const size_t BBF_OFF  = 28459264;          // 16777216
  const size_t PMAX_OFF = 45236480;          // 524288
  const size_t PIDX_OFF = 45760768;          // 524288    end ~46.3 MB

  unsigned short* hmb = (unsigned short*)(ws + HMB_OFF);
  unsigned short* Wsw = (unsigned short*)(ws + WSW_OFF);
  unsigned short* wob = (unsigned short*)(ws + WOB_OFF);
  float* om  = (float*)(ws + OM_OFF);
  float* z1  = (float*)(ws + Z1_OFF);
  float* z2  = (float*)(ws + Z2_OFF);
  int*   flg = (int*)(ws + FLAG_OFF);
  float* rad = (float*)(ws + RAD_OFF);
  unsigned short* obf = (unsigned short*)(ws + OBF_OFF);
  unsigned short* bbf = (unsigned short*)(ws + BBF_OFF);
  float* pmax = (float*)(ws + PMAX_OFF);
  int*   pidx = (int*)(ws + PIDX_OFF);

  float* out0 = (float*)d_out;            // [T,D] obs_beliefs
  float* out1 = out0 + (size_t)TT*DD;     // [T] sims_out
  float* out2 = out1 + TT;                // [T] slots
  float* out3 = out2 + TT;                // [T] meaningful

  hipMemsetAsync(ws + Z1_OFF, 0, 2*MM*sizeof(float) + 256, stream);  // z1,z2,flag

  k_mean    <<<TT*HH/4/256, 256, 0, stream>>>(hidden, hmb);
  k_cvt_w   <<<(1024*HH/8)/256, 256, 0, stream>>>(W_g1, W_p1, Wsw);
  k_cvt_wobs<<<(DD*HH/4)/256, 256, 0, stream>>>(W_obs, wob);
  k_obs     <<<dim3(DD/128, TT/128), 256, 0, stream>>>(hmb, wob, om);
  k_gp      <<<512, 256, 0, stream>>>(hidden, Wsw, b_g1, b_p1, W_g2, W_p2, z1, z2);
  k_obs_fin <<<TT/4, 256, 0, stream>>>(om, z1, z2, b_g2, b_p2, out0, out3, rad, obf);
  k_beliefs <<<NN/4, 256, 0, stream>>>(beliefs, bbf);
  k_any     <<<NN/256, 256, 0, stream>>>(amask, flg);
  k_sims    <<<1024, 256, 0, stream>>>(obf, bbf, amask, pmax, pidx);
  k_combine <<<TT/256, 256, 0, stream>>>(pmax, pidx, rad, flg, out1, out2);
}

// Round 5
// 502.134 us; speedup vs baseline: 1.5114x; 1.0182x over previous
//
#include <hip/hip_runtime.h>
#include <hip/hip_bf16.h>
#include <math.h>

#define TB 4
#define TT 4096
#define HH 2048
#define DD 256
#define NN 32768
#define HQ 512
#define MM (TB*TT)

typedef __attribute__((ext_vector_type(8))) short bf16x8;
typedef __attribute__((ext_vector_type(8))) _Float16 f16x8;
typedef __attribute__((ext_vector_type(4))) float f32x4;

__device__ inline unsigned short f2bf(float x){
  __hip_bfloat16 h = __float2bfloat16(x);
  return *reinterpret_cast<unsigned short*>(&h);
}

__device__ inline unsigned short f2h(float x){
  _Float16 h = (_Float16)x;
  unsigned short u; __builtin_memcpy(&u, &h, 2); return u;
}

__device__ inline bf16x8 as_bf16x8(uint4 u){ bf16x8 r; __builtin_memcpy(&r,&u,16); return r; }

// async global->LDS DMA, 16B per lane. LDS dest = wave-uniform base + lane*16.
__device__ __forceinline__ void gload_ldsv(const void* g, void* l){
  __builtin_amdgcn_global_load_lds(
      (const __attribute__((address_space(1))) unsigned int*)g,
      (__attribute__((address_space(3))) unsigned int*)l, 16, 0, 0);
}

// K1: batch-mean only (bf16 out)
__global__ __launch_bounds__(256) void k_mean(const float* __restrict__ h,
    unsigned short* __restrict__ hmb){
  const size_t i = (size_t)blockIdx.x*256 + threadIdx.x;   // float4 idx in [T*H/4]
  const size_t TH4 = (size_t)TT*HH/4;
  const float4* p = (const float4*)h;
  float4 v0 = p[i], v1 = p[i+TH4], v2 = p[i+2*TH4], v3 = p[i+3*TH4];
  float4 m;
  m.x = 0.25f*(v0.x+v1.x+v2.x+v3.x);
  m.y = 0.25f*(v0.y+v1.y+v2.y+v3.y);
  m.z = 0.25f*(v0.z+v1.z+v2.z+v3.z);
  m.w = 0.25f*(v0.w+v1.w+v2.w+v3.w);
  ushort4 o; o.x = f2bf(m.x); o.y = f2bf(m.y); o.z = f2bf(m.z); o.w = f2bf(m.w);
  *(ushort4*)(hmb + i*4) = o;
}

// K_prep: fused preprocessing — cvt_w (1024 blocks) + cvt_wobs (512) +
// beliefs-normalize (8192) + any-active (128). Bodies unchanged; fusion cuts
// 3 kernel launches of serialization overhead.
#define PREP_CVTW 1024
#define PREP_WOBS 512
#define PREP_BEL  8192
#define PREP_ANY  128
__global__ __launch_bounds__(256) void k_prep(
    const float* __restrict__ Wg1, const float* __restrict__ Wp1,
    unsigned short* __restrict__ Wsw,
    const float* __restrict__ Wobs, unsigned short* __restrict__ wob,
    const float* __restrict__ bel, unsigned short* __restrict__ bbf,
    const unsigned char* __restrict__ mask, int* __restrict__ flag){
  const int b = blockIdx.x;
  if (b < PREP_CVTW){
    // W_g1||W_p1 -> fp16, pre-swizzled tile-linear layout for k_gp
    const int id = b*256 + threadIdx.x;
    const int n = id >> 8;
    const int cg = id & 255;
    const int k = cg*8;
    const int kc = cg >> 2;
    const int c8 = cg & 3;
    const float* src = (n < HQ) ? (Wg1 + (size_t)n*HH + k) : (Wp1 + (size_t)(n-HQ)*HH + k);
    float4 v0 = *(const float4*)src;
    float4 v1 = *(const float4*)(src + 4);
    unsigned short o[8] = {f2h(v0.x),f2h(v0.y),f2h(v0.z),f2h(v0.w),
                           f2h(v1.x),f2h(v1.y),f2h(v1.z),f2h(v1.w)};
    const int nb = n >> 8, r = n & 255;
    const int s = (r & 3) ^ ((r >> 2) & 3);
    unsigned short* dst = Wsw + ((size_t)(nb*64 + kc))*8192 + r*32 + ((c8 ^ s) << 3);
    __builtin_memcpy(dst, o, 16);
  } else if (b < PREP_CVTW + PREP_WOBS){
    // W_obs -> bf16
    const int idx4 = (b - PREP_CVTW)*256 + threadIdx.x;
    float4 v = *(const float4*)(Wobs + (size_t)idx4*4);
    ushort4 o; o.x = f2bf(v.x); o.y = f2bf(v.y); o.z = f2bf(v.z); o.w = f2bf(v.w);
    *(ushort4*)(wob + (size_t)idx4*4) = o;
  } else if (b < PREP_CVTW + PREP_WOBS + PREP_BEL){
    // beliefs -> bf16 angles
    const int bb = b - (PREP_CVTW + PREP_WOBS);
    const int n = (bb*256 + threadIdx.x) >> 6;
    const int lane = threadIdx.x & 63;
    const float4 v = *(const float4*)(bel + (size_t)n*DD + lane*4);
    float s = v.x*v.x + v.y*v.y + v.z*v.z + v.w*v.w;
    #pragma unroll
    for (int m = 1; m < 64; m <<= 1) s += __shfl_xor(s, m);
    const float inv = 1.f / fmaxf(sqrtf(s), 1e-8f);
    ushort4 o;
    o.x = f2bf(v.x*inv); o.y = f2bf(v.y*inv); o.z = f2bf(v.z*inv); o.w = f2bf(v.w*inv);
    *(ushort4*)(bbf + (size_t)n*DD + lane*4) = o;
  } else {
    // any_active flag
    const int i = (b - (PREP_CVTW + PREP_WOBS + PREP_BEL))*256 + threadIdx.x;
    const int any = (mask[i] != 0) ? 1 : 0;
    if (__ballot(any)){
      if ((threadIdx.x & 63) == 0) atomicOr(flag, 1);
    }
  }
}

// K3: obs_mean = hmb @ wob^T  (bf16 MFMA)  [4096,2048]x[256,2048]^T
// Full-DMA template (k_gp r4 pattern): both tiles staged via global_load_lds
// into double buffers, next-tile DMA issued before compute, one barrier/step.
// XOR swizzle via global source (rule #21): LDS slot s of row r holds global
// chunk s^(r&3); read uses slot q^(lr&3).
__global__ __launch_bounds__(256) void k_obs(const unsigned short* __restrict__ A,
    const unsigned short* __restrict__ Bw, float* __restrict__ C){
  const int n0 = blockIdx.x*128, m0 = blockIdx.y*128;
  const int tid = threadIdx.x;
  const int w = tid>>6, lane = tid&63, lr = lane&15, q = lane>>4;
  __shared__ __align__(16) unsigned short As[2][4096];   // 2 x 8 KB
  __shared__ __align__(16) unsigned short Bs[2][4096];   // 2 x 8 KB
  f32x4 acc[2][8] = {};
  const int srow = lane >> 2;                 // 0..15
  const int sch  = (lane & 3) ^ (srow & 3);   // inverse-swizzled global chunk
  const unsigned short* asrc = A  + (size_t)(m0 + w*32 + srow)*HH + sch*8;
  const unsigned short* bsrc = Bw + (size_t)(n0 + w*32 + srow)*HH + sch*8;

  #pragma unroll
  for (int i = 0; i < 2; i++){
    gload_ldsv(asrc + (size_t)i*16*HH, &As[0][(w*32 + i*16)*32]);
    gload_ldsv(bsrc + (size_t)i*16*HH, &Bs[0][(w*32 + i*16)*32]);
  }
  __syncthreads();

  for (int t = 0; t < 64; t++){
    const int cur = t & 1;
    if (t < 63){
      const int ko = (t+1)*32;
      #pragma unroll
      for (int i = 0; i < 2; i++){
        gload_ldsv(asrc + (size_t)i*16*HH + ko, &As[cur^1][(w*32 + i*16)*32]);
        gload_ldsv(bsrc + (size_t)i*16*HH + ko, &Bs[cur^1][(w*32 + i*16)*32]);
      }
    }
    bf16x8 a[2];
    #pragma unroll
    for (int i = 0; i < 2; i++)
      a[i] = as_bf16x8(*(const uint4*)&As[cur][(w*32 + i*16 + lr)*32 + ((q ^ (lr&3))<<3)]);
    #pragma unroll
    for (int j = 0; j < 8; j++){
      bf16x8 bb = as_bf16x8(*(const uint4*)&Bs[cur][(j*16 + lr)*32 + ((q ^ (lr&3))<<3)]);
      #pragma unroll
      for (int i = 0; i < 2; i++)
        acc[i][j] = __builtin_amdgcn_mfma_f32_16x16x32_bf16(a[i], bb, acc[i][j], 0, 0, 0);
    }
    __syncthreads();
  }
  #pragma unroll
  for (int i = 0; i < 2; i++)
    #pragma unroll
    for (int j = 0; j < 8; j++)
      #pragma unroll
      for (int r = 0; r < 4; r++)
        C[(size_t)(m0 + w*32 + i*16 + q*4 + r)*DD + n0 + j*16 + lr] = acc[i][j][r];
}

// K4: gate/prec layer1 — UNCHANGED from round 4 (verified 120.5 µs, MfmaUtil 52%).
__global__ __launch_bounds__(256, 2) void k_gp(const float* __restrict__ A,
    const unsigned short* __restrict__ Wsw,
    const float* __restrict__ bg1, const float* __restrict__ bp1,
    const float* __restrict__ Wg2, const float* __restrict__ Wp2,
    float* __restrict__ z1, float* __restrict__ z2){
  const int bid = blockIdx.x;
  const int nb = (bid >> 3) & 3;
  const int my = (bid & 7) + ((bid >> 5) << 3);
  const int m0 = my*128;
  const int tid = threadIdx.x;
  const int w = tid>>6, lane = tid&63, lr = lane&15, q = lane>>4;
  __shared__ __align__(16) unsigned short Ws[2][8192];   // 2 x 16 KB W tiles
  __shared__ __align__(16) float As[2][4096];            // 2 x 16 KB A tiles
  f32x4 acc[2][16] = {};

  const unsigned short* wt = Wsw + (size_t)nb*64*8192 + w*2048 + lane*8;
  const int rpB = lr*32 + ((q ^ ((lr & 3) ^ ((lr >> 2) & 3))) << 3);
  const int sr8 = lane >> 3;
  const int sc  = (lane & 7) ^ sr8;
  const float* asrc = A + (size_t)(m0 + w*32 + sr8)*HH + sc*4;

  #pragma unroll
  for (int i = 0; i < 4; i++){
    gload_ldsv(wt + i*512, &Ws[0][w*2048 + i*512]);
    gload_ldsv(asrc + (size_t)i*8*HH, &As[0][(w*32 + i*8)*32]);
  }
  __syncthreads();

  for (int t = 0; t < 64; t++){
    const int cur = t & 1;
    if (t < 63){
      #pragma unroll
      for (int i = 0; i < 4; i++){
        gload_ldsv(wt + (size_t)(t+1)*8192 + i*512, &Ws[cur^1][w*2048 + i*512]);
        gload_ldsv(asrc + (size_t)i*8*HH + (t+1)*32, &As[cur^1][(w*32 + i*8)*32]);
      }
    }
    const float* At = As[cur];
    f16x8 ah[2], al[2];
    #pragma unroll
    for (int i = 0; i < 2; i++){
      const int tr = w*32 + i*16 + lr;
      const int px = lr & 7;
      float4 fa = *(const float4*)&At[tr*32 + (((2*q)   ^ px) << 2)];
      float4 fb = *(const float4*)&At[tr*32 + (((2*q+1) ^ px) << 2)];
      float av[8] = {fa.x,fa.y,fa.z,fa.w, fb.x,fb.y,fb.z,fb.w};
      #pragma unroll
      for (int e = 0; e < 8; e++){
        _Float16 h = (_Float16)av[e];
        ah[i][e] = h; al[i][e] = (_Float16)(av[e] - (float)h);
      }
    }
    const unsigned short* Wc = Ws[cur];
    __builtin_amdgcn_s_setprio(1);
    #pragma unroll
    for (int j = 0; j < 16; j++){
      f16x8 bh;
      __builtin_memcpy(&bh, Wc + j*512 + rpB, 16);
      acc[0][j] = __builtin_amdgcn_mfma_f32_16x16x32_f16(ah[0], bh, acc[0][j], 0, 0, 0);
      acc[1][j] = __builtin_amdgcn_mfma_f32_16x16x32_f16(ah[1], bh, acc[1][j], 0, 0, 0);
      acc[0][j] = __builtin_amdgcn_mfma_f32_16x16x32_f16(al[0], bh, acc[0][j], 0, 0, 0);
      acc[1][j] = __builtin_amdgcn_mfma_f32_16x16x32_f16(al[1], bh, acc[1][j], 0, 0, 0);
    }
    __builtin_amdgcn_s_setprio(0);
    __syncthreads();
  }

  const bool isP = (nb >= 2);
  const float* b1 = isP ? bp1 : bg1;
  const float* w2 = isP ? Wp2 : Wg2;
  float* zt = isP ? z2 : z1;
  const int nbl = nb*256 - (isP ? HQ : 0);
  float s[2][4] = {};
  #pragma unroll
  for (int j = 0; j < 16; j++){
    const int n = nbl + j*16 + lr;
    const float bb = b1[n], ww = w2[n];
    #pragma unroll
    for (int i = 0; i < 2; i++)
      #pragma unroll
      for (int r = 0; r < 4; r++)
        s[i][r] += fmaxf(acc[i][j][r] + bb, 0.f) * ww;
  }
  #pragma unroll
  for (int mk = 1; mk < 16; mk <<= 1)
    #pragma unroll
    for (int i = 0; i < 2; i++)
      #pragma unroll
      for (int r = 0; r < 4; r++)
        s[i][r] += __shfl_xor(s[i][r], mk);
  if (lr == 0){
    #pragma unroll
    for (int i = 0; i < 2; i++)
      #pragma unroll
      for (int r = 0; r < 4; r++)
        atomicAdd(&zt[m0 + w*32 + i*16 + q*4 + r], s[i][r]);
  }
}

// K5: per-t finalize — one wave per t, shuffle reductions (no barriers)
__global__ __launch_bounds__(256) void k_obs_fin(const float* __restrict__ obs_mean,
    const float* __restrict__ z1, const float* __restrict__ z2,
    const float* __restrict__ bg2, const float* __restrict__ bp2,
    float* __restrict__ out0, float* __restrict__ out3,
    float* __restrict__ obs_radii, unsigned short* __restrict__ obf){
  const int w = threadIdx.x >> 6, lane = threadIdx.x & 63;
  const int t = blockIdx.x*4 + w;
  float pm = 0.f;
  if (lane < TB){
    float a = z1[lane*TT + t] + bg2[0];
    float b = z2[lane*TT + t] + bp2[0];
    float gate = 1.f/(1.f + expf(-a));
    float sp = (b > 0.f) ? (b + log1pf(expf(-b))) : log1pf(expf(b));
    pm = gate * sp;
  }
  #pragma unroll
  for (int m = 1; m < 4; m <<= 1) pm += __shfl_xor(pm, m);
  pm = __shfl(pm, 0) * 0.25f;
  float4 x = *(const float4*)(obs_mean + (size_t)t*DD + lane*4);
  float ss = x.x*x.x + x.y*x.y + x.z*x.z + x.w*x.w;
  #pragma unroll
  for (int m = 1; m < 64; m <<= 1) ss += __shfl_xor(ss, m);
  const float nrm = sqrtf(ss);
  const float sc = pm / fmaxf(nrm, 1e-8f);
  float4 ob = {x.x*sc, x.y*sc, x.z*sc, x.w*sc};
  *(float4*)(out0 + (size_t)t*DD + lane*4) = ob;
  float s2 = ob.x*ob.x + ob.y*ob.y + ob.z*ob.z + ob.w*ob.w;
  #pragma unroll
  for (int m = 1; m < 64; m <<= 1) s2 += __shfl_xor(s2, m);
  const float r2 = sqrtf(s2);
  if (lane == 0){
    obs_radii[t] = r2;
    out3[t] = (r2 > 0.05f) ? 1.f : 0.f;
  }
  const float inv2 = 1.f / fmaxf(r2, 1e-8f);
  ushort4 o = {f2bf(ob.x*inv2), f2bf(ob.y*inv2), f2bf(ob.z*inv2), f2bf(ob.w*inv2)};
  *(ushort4*)(obf + (size_t)t*DD + lane*4) = o;
}

// K7: fused sims + masked max/argmax. Async DMA double-buffer, one barrier
// per tile, XCD-grouped grid (xcd = ns&7).
// NEW: 32-row tiles (2x16 KB LDS + 1 KB mask = 34 KB -> 4 blocks/CU = 4
// waves/SIMD, was 2); mask slice hoisted to LDS once (removes 64 dependent
// global byte-loads per wave); s_setprio around the MFMA cluster (T5 regime:
// independent blocks at different phases).
__global__ __launch_bounds__(256) void k_sims(const unsigned short* __restrict__ obf,
    const unsigned short* __restrict__ bbf, const unsigned char* __restrict__ mask,
    float* __restrict__ pmax, int* __restrict__ pidx){
  const int bid = blockIdx.x;                // 0..1023
  const int rest = bid >> 3;
  const int ns = (bid & 7) + ((rest >> 5) << 3);   // 0..31; xcd = ns&7
  const int t0 = (rest & 31) * 128;
  const int nbase0 = ns * (NN/32);           // 1024-row slice
  const int tid = threadIdx.x;
  const int w = tid >> 6, lane = tid & 63;
  const int lr = lane & 15, q = lane >> 4;
  __shared__ __align__(16) unsigned short bt[2][32*256];   // 2 x 16 KB
  __shared__ __align__(16) unsigned char am[1024];
  const int srow = lane >> 5;
  const int sp   = lane & 31;

  // mask slice -> LDS once
  ((unsigned int*)am)[tid] = ((const unsigned int*)(mask + nbase0))[tid];

  // prologue: stage tile 0 (32 rows, 4 DMA instrs/wave)
  #pragma unroll
  for (int i = 0; i < 4; i++){
    const int row = (i*4 + w)*2 + srow;
    const unsigned short* src = bbf + (size_t)(nbase0 + row)*DD + ((sp ^ (row & 31)) << 3);
    gload_ldsv(src, &bt[0][(i*4 + w)*512]);
  }
  // A fragments into registers (latency overlaps the DMA)
  bf16x8 afr[2][8];
  #pragma unroll
  for (int i = 0; i < 2; i++){
    const unsigned short* ap = obf + (size_t)(t0 + w*32 + i*16 + lr)*DD + q*8;
    #pragma unroll
    for (int ks = 0; ks < 8; ks++)
      afr[i][ks] = as_bf16x8(*(const uint4*)(ap + ks*32));
  }
  __syncthreads();   // tile 0 + am + afr ready

  float vmax[2][4] = {{-INFINITY,-INFINITY,-INFINITY,-INFINITY},
                      {-INFINITY,-INFINITY,-INFINITY,-INFINITY}};
  int   vidx[2][4] = {{-1,-1,-1,-1},{-1,-1,-1,-1}};
  int cur = 0;
  for (int it = 0; it < 32; it++){
    const int nl = it*32;                    // slice-local tile base
    if (it < 31){
      #pragma unroll
      for (int i = 0; i < 4; i++){
        const int row = (i*4 + w)*2 + srow;
        const unsigned short* src = bbf + (size_t)(nbase0 + nl + 32 + row)*DD + ((sp ^ (row & 31)) << 3);
        gload_ldsv(src, &bt[cur^1][(i*4 + w)*512]);
      }
    }
    const unsigned short* btc = bt[cur];
    #pragma unroll
    for (int sub = 0; sub < 2; sub++){
      const int rowi = sub*16 + lr;          // 0..31
      const bool act = (am[nl + rowi] != 0);
      const unsigned short* bp = btc + rowi*256;
      f32x4 acc[2] = {{0.f,0.f,0.f,0.f},{0.f,0.f,0.f,0.f}};
      __builtin_amdgcn_s_setprio(1);
      #pragma unroll
      for (int ks = 0; ks < 8; ks++){
        const int p = (q + ks*4) ^ rowi;
        bf16x8 bfr = as_bf16x8(*(const uint4*)(bp + (p & 31)*8));
        acc[0] = __builtin_amdgcn_mfma_f32_16x16x32_bf16(afr[0][ks], bfr, acc[0], 0, 0, 0);
        acc[1] = __builtin_amdgcn_mfma_f32_16x16x32_bf16(afr[1][ks], bfr, acc[1], 0, 0, 0);
      }
      __builtin_amdgcn_s_setprio(0);
      if (act){
        const int n = nbase0 + nl + rowi;
        #pragma unroll
        for (int i = 0; i < 2; i++)
          #pragma unroll
          for (int r = 0; r < 4; r++)
            if (acc[i][r] > vmax[i][r]){ vmax[i][r] = acc[i][r]; vidx[i][r] = n; }
      }
    }
    __syncthreads();   // reads of bt[cur] done AND tile(it+1) DMA drained
    cur ^= 1;
  }
  #pragma unroll
  for (int mk = 1; mk < 16; mk <<= 1){
    #pragma unroll
    for (int i = 0; i < 2; i++)
      #pragma unroll
      for (int r = 0; r < 4; r++){
        float om = __shfl_xor(vmax[i][r], mk);
        int   oi = __shfl_xor(vidx[i][r], mk);
        if (om > vmax[i][r] || (om == vmax[i][r] && (unsigned)oi < (unsigned)vidx[i][r])){
          vmax[i][r] = om; vidx[i][r] = oi;
        }
      }
  }
  if (lr == 0){
    #pragma unroll
    for (int i = 0; i < 2; i++)
      #pragma unroll
      for (int r = 0; r < 4; r++){
        const int t = t0 + w*32 + i*16 + q*4 + r;
        pmax[ns*TT + t] = vmax[i][r];
        pidx[ns*TT + t] = vidx[i][r];
      }
  }
}

// K8: combine n-splits + match logic
__global__ __launch_bounds__(256) void k_combine(const float* __restrict__ pmax,
    const int* __restrict__ pidx, const float* __restrict__ obs_radii,
    const int* __restrict__ flag, float* __restrict__ out1, float* __restrict__ out2){
  const int t = blockIdx.x*256 + threadIdx.x;
  float best = -INFINITY; int bi = -1;
  #pragma unroll
  for (int s = 0; s < 32; s++){
    float m = pmax[s*TT + t];
    if (m > best){ best = m; bi = pidx[s*TT + t]; }
  }
  const bool anyA = (flag[0] != 0);
  const bool mf = obs_radii[t] > 0.05f;
  const bool matched = mf && anyA && (best > 0.5f);
  out1[t] = matched ? best : 0.f;
  out2[t] = matched ? (float)bi : -1.f;
}

extern "C" void kernel_launch(void* const* d_in, const int* in_sizes, int n_in,
                              void* d_out, int out_size, void* d_ws, size_t ws_size,
                              hipStream_t stream) {
  const float* hidden = (const float*)d_in[0];
  const float* beliefs = (const float*)d_in[1];
  const unsigned char* amask = (const unsigned char*)d_in[2];
  const float* W_obs = (const float*)d_in[3];
  const float* W_g1 = (const float*)d_in[4];
  const float* b_g1 = (const float*)d_in[5];
  const float* W_g2 = (const float*)d_in[6];
  const float* b_g2 = (const float*)d_in[7];
  const float* W_p1 = (const float*)d_in[8];
  const float* b_p1 = (const float*)d_in[9];
  const float* W_p2 = (const float*)d_in[10];
  const float* b_p2 = (const float*)d_in[11];

  char* ws = (char*)d_ws;
  const size_t HMB_OFF  = 0;                 // 16777216
  const size_t WSW_OFF  = 16777216;          // 4194304 (swizzled)
  const size_t WOB_OFF  = 20971520;          // 1048576
  const size_t OM_OFF   = 22020096;          // 4194304
  const size_t Z1_OFF   = 26214400;          // 65536
  const size_t Z2_OFF   = 26279936;          // 65536
  const size_t FLAG_OFF = 26345472;          // 256
  const size_t RAD_OFF  = 26345728;          // 16384
  const size_t OBF_OFF  = 26362112;          // 2097152
  const size_t BBF_OFF  = 28459264;          // 16777216
  const size_t PMAX_OFF = 45236480;          // 524288
  const size_t PIDX_OFF = 45760768;          // 524288    end ~46.3 MB

  unsigned short* hmb = (unsigned short*)(ws + HMB_OFF);
  unsigned short* Wsw = (unsigned short*)(ws + WSW_OFF);
  unsigned short* wob = (unsigned short*)(ws + WOB_OFF);
  float* om  = (float*)(ws + OM_OFF);
  float* z1  = (float*)(ws + Z1_OFF);
  float* z2  = (float*)(ws + Z2_OFF);
  int*   flg = (int*)(ws + FLAG_OFF);
  float* rad = (float*)(ws + RAD_OFF);
  unsigned short* obf = (unsigned short*)(ws + OBF_OFF);
  unsigned short* bbf = (unsigned short*)(ws + BBF_OFF);
  float* pmax = (float*)(ws + PMAX_OFF);
  int*   pidx = (int*)(ws + PIDX_OFF);

  float* out0 = (float*)d_out;            // [T,D] obs_beliefs
  float* out1 = out0 + (size_t)TT*DD;     // [T] sims_out
  float* out2 = out1 + TT;                // [T] slots
  float* out3 = out2 + TT;                // [T] meaningful

  hipMemsetAsync(ws + Z1_OFF, 0, 2*MM*sizeof(float) + 256, stream);  // z1,z2,flag

  k_prep    <<<PREP_CVTW + PREP_WOBS + PREP_BEL + PREP_ANY, 256, 0, stream>>>(
                W_g1, W_p1, Wsw, W_obs, wob, beliefs, bbf, amask, flg);
  k_mean    <<<TT*HH/4/256, 256, 0, stream>>>(hidden, hmb);
  k_obs     <<<dim3(DD/128, TT/128), 256, 0, stream>>>(hmb, wob, om);
  k_gp      <<<512, 256, 0, stream>>>(hidden, Wsw, b_g1, b_p1, W_g2, W_p2, z1, z2);
  k_obs_fin <<<TT/4, 256, 0, stream>>>(om, z1, z2, b_g2, b_p2, out0, out3, rad, obf);
  k_sims    <<<1024, 256, 0, stream>>>(obf, bbf, amask, pmax, pidx);
  k_combine <<<TT/256, 256, 0, stream>>>(pmax, pidx, rad, flg, out1, out2);
}